// Round 2
// baseline (413.185 us; speedup 1.0000x reference)
//
#include <hip/hip_runtime.h>
#include <hip/hip_bf16.h>

// WorkflowGNN: GCN(32->64)+ReLU, GAT(64->64,h=1)+ReLU, GCN(64->64)+ReLU,
// heads: opt [N,10], bottleneck [N,1], mean-embed [64]. f32 in/out.
// R18 (fixed): k_hist (61us, 18% BW, 66MB write = ~1 evicted line/edge)
// replaced by 2-pass: k_part streams edges ONCE into 8 dst-range buckets
// (LDS-aggregated cursors, ~10K global atomics, coalesced pair writes,
// overlays hbuf), then k_fill fills adj per-bucket on its home XCD: window
// 3.2MB < 4MB L2 so scattered stores merge before eviction.
// Fix vs failed run: __builtin_nontemporal_load needs scalar/ext-vector
// pointee; HIP uint4 is a class -> use ext_vector_type(4) alias uvec4.

#define CAP 64
#define NBUK 8

typedef unsigned uvec4 __attribute__((ext_vector_type(4)));

__device__ __forceinline__ int uwave(){                 // wave id, known-uniform
  return __builtin_amdgcn_readfirstlane(threadIdx.x >> 6);
}
__device__ __forceinline__ unsigned short f2bf(float f){ // RNE, finite inputs
  unsigned u = __float_as_uint(f);
  return (unsigned short)((u + 0x7fffu + ((u >> 16) & 1u)) >> 16);
}
__device__ __forceinline__ float bfl(unsigned u){ return __uint_as_float(u << 16); }
__device__ __forceinline__ float bfh(unsigned u){ return __uint_as_float(u & 0xffff0000u); }

// setup: zero cnt/bcnt/pad-rows/emb_acc, pack Wcat/bcat
__global__ void k_setup(const float* __restrict__ Wopt, const float* __restrict__ bopt,
                        const float* __restrict__ Wb1, const float* __restrict__ bb1,
                        float* __restrict__ Wcat, float* __restrict__ bcat,
                        int* __restrict__ cnt, int* __restrict__ bcnt,
                        unsigned short* __restrict__ tb,
                        unsigned short* __restrict__ xh, float* __restrict__ emb_acc,
                        int n){
  int i = blockIdx.x*blockDim.x + threadIdx.x;
  if (i < n) cnt[i] = 0;
  if (blockIdx.x == 0){
    int tid = threadIdx.x;
    for (int j = tid; j < 4096; j += 256){    // pack head weights
      int f = j >> 6, c = j & 63;
      float w = 0.f;
      if (c < 10)       w = Wopt[f*10 + c];
      else if (c >= 32) w = Wb1[f*32 + (c-32)];
      Wcat[j] = w;
    }
    if (tid < 64){
      float b = 0.f;
      if (tid < 10)       b = bopt[tid];
      else if (tid >= 32) b = bb1[tid-32];
      bcat[tid] = b;
      tb[(size_t)n*64 + tid] = 0;             // zero pad row (64-feat)
      emb_acc[tid] = 0.f;
    }
    if (tid >= 64 && tid < 96) xh[(size_t)n*32 + (tid-64)] = 0;  // zero pad row (32-feat)
    if (tid >= 96 && tid < 96 + NBUK) bcnt[tid-96] = 0;          // bucket cursors
  }
}

// pass A: partition edges into NBUK dst-range buckets. One coalesced read of
// src/dst (int4), LDS-aggregated cursors -> ~8 global atomics per block.
// Bucket id from float mul is a locality heuristic only (pass B uses stored dst).
__global__ __launch_bounds__(256) void k_part(const int* __restrict__ src,
                        const int* __restrict__ dst,
                        uint2* __restrict__ pairs, int* __restrict__ bcnt,
                        int e, int pbcap, float binv){
  __shared__ int lcnt[NBUK];
  __shared__ int lbase[NBUK];
  int tid = threadIdx.x;
  if (tid < NBUK) lcnt[tid] = 0;
  __syncthreads();
  int i0 = blockIdx.x*1024 + tid*4;
  int d[4], s[4], bk[4], lp[4];
  int nv = e - i0;
  if (nv > 4) nv = 4;
  if (nv == 4){
    int4 dd = *(const int4*)(dst + i0);
    int4 ss = *(const int4*)(src + i0);
    d[0]=dd.x; d[1]=dd.y; d[2]=dd.z; d[3]=dd.w;
    s[0]=ss.x; s[1]=ss.y; s[2]=ss.z; s[3]=ss.w;
  } else {
    #pragma unroll
    for (int j = 0; j < 4; j++){ d[j] = 0; s[j] = 0; }
    for (int j = 0; j < nv; j++){ d[j] = dst[i0+j]; s[j] = src[i0+j]; }
  }
  #pragma unroll
  for (int j = 0; j < 4; j++){
    if (j < nv){
      bk[j] = min(NBUK-1, (int)((float)d[j] * binv));
      lp[j] = atomicAdd(&lcnt[bk[j]], 1);
    }
  }
  __syncthreads();
  if (tid < NBUK) lbase[tid] = atomicAdd(&bcnt[tid], lcnt[tid]);
  __syncthreads();
  #pragma unroll
  for (int j = 0; j < 4; j++){
    if (j < nv){
      int p = lbase[bk[j]] + lp[j];
      if (p < pbcap)
        pairs[(size_t)bk[j]*pbcap + p] = make_uint2((unsigned)d[j], (unsigned)s[j]);
    }
  }
}

// pass B: fill adj from one bucket per blockIdx%8 (home-XCD heuristic).
// adj window per bucket = (n/8)*256B = 3.2MB < 4MB L2 -> stores merge.
// 2 pairs/thread/iter keeps two returning atomics in flight.
__global__ __launch_bounds__(256) void k_fill(const uint2* __restrict__ pairs,
                        const int* __restrict__ bcnt, int* __restrict__ cnt,
                        int* __restrict__ adj, int pbcap){
  int b = blockIdx.x & (NBUK-1);
  int m = bcnt[b];
  if (m > pbcap) m = pbcap;
  const uvec4* pb = (const uvec4*)(pairs + (size_t)b*pbcap);
  int half = (m + 1) >> 1;
  int tpb = (gridDim.x >> 3) * 256;
  for (int j = (blockIdx.x >> 3)*256 + threadIdx.x; j < half; j += tpb){
    uvec4 p = __builtin_nontemporal_load(pb + j);
    int pos0 = atomicAdd(&cnt[p.x], 1);
    bool ok1 = (2*j + 1) < m;
    int pos1 = ok1 ? atomicAdd(&cnt[p.z], 1) : 0;
    if (pos0 < CAP) adj[(size_t)p.x*CAP + pos0] = (int)p.y;
    if (ok1 && pos1 < CAP) adj[(size_t)p.z*CAP + pos1] = (int)p.w;
  }
}

// cast x -> bf16, pre-scaled by rsqrt(deg): xs[v] = x[v]*rsqrt(cnt[v]+1)
__global__ void k_castscale(const float* __restrict__ x, const int* __restrict__ cnt,
                            unsigned short* __restrict__ xh, int total4){
  int i = blockIdx.x*blockDim.x + threadIdx.x;
  if (i >= total4) return;
  int row = i >> 3;                           // 8 float4 per 32-elem row
  float dv = rsqrtf((float)(cnt[row] + 1));
  float4 v = ((const float4*)x)[i];
  uint2 o;
  o.x = (unsigned)f2bf(v.x*dv) | ((unsigned)f2bf(v.y*dv) << 16);
  o.y = (unsigned)f2bf(v.z*dv) | ((unsigned)f2bf(v.w*dv) << 16);
  ((uint2*)xh)[i] = o;
}

// layer-1 FUSED aggregate+gemm, DUAL-NODE, bf16 out.
__global__ __launch_bounds__(256) void k_agg32g(const unsigned short* __restrict__ xh,
                          const int* __restrict__ adj, const int* __restrict__ cnt,
                          const float* __restrict__ W1, const float* __restrict__ b1,
                          unsigned short* __restrict__ h, int n){
  int lane = threadIdx.x & 63;
  float wreg[32];
  #pragma unroll
  for (int k = 0; k < 32; k++) wreg[k] = W1[k*64 + lane];  // coalesced, once
  float br = b1[lane];
  int v0 = blockIdx.x*8 + uwave()*2;
  if (v0 >= n) return;                        // uniform
  int v1 = v0 + 1;
  bool has1 = v1 < n;
  if (!has1) v1 = v0;
  int cn0 = cnt[v0], cn1 = cnt[v1];
  int c0 = min(cn0, CAP), c1 = min(cn1, CAP);
  int ureg0 = n, ureg1 = n;                   // pad -> zero row
  if (lane < c0) ureg0 = (adj + (size_t)v0*CAP)[lane];
  if (lane < c1) ureg1 = (adj + (size_t)v1*CAP)[lane];
  int g = lane >> 3, q = lane & 7;
  float4 a0 = {0.f,0.f,0.f,0.f}, a1 = {0.f,0.f,0.f,0.f};
  int itm = (max(c0, c1) + 7) >> 3;
  #pragma unroll 2
  for (int jj = 0; jj < itm; jj++){
    int u0 = __shfl(ureg0, jj*8 + g);         // pad iters -> zero row (L1-hot)
    int u1 = __shfl(ureg1, jj*8 + g);
    uint2 r0 = ((const uint2*)(xh + (size_t)u0*32))[q];   // both loads in flight
    uint2 r1 = ((const uint2*)(xh + (size_t)u1*32))[q];
    a0.x += bfl(r0.x); a0.y += bfh(r0.x); a0.z += bfl(r0.y); a0.w += bfh(r0.y);
    a1.x += bfl(r1.x); a1.y += bfh(r1.x); a1.z += bfl(r1.y); a1.w += bfh(r1.y);
  }
  #pragma unroll
  for (int off = 8; off <= 32; off <<= 1){
    a0.x += __shfl_xor(a0.x, off); a0.y += __shfl_xor(a0.y, off);
    a0.z += __shfl_xor(a0.z, off); a0.w += __shfl_xor(a0.w, off);
    a1.x += __shfl_xor(a1.x, off); a1.y += __shfl_xor(a1.y, off);
    a1.z += __shfl_xor(a1.z, off); a1.w += __shfl_xor(a1.w, off);
  }
  uint2 s0 = ((const uint2*)(xh + (size_t)v0*32))[q];     // self rows (pre-scaled)
  uint2 s1 = ((const uint2*)(xh + (size_t)v1*32))[q];
  a0.x += bfl(s0.x); a0.y += bfh(s0.x); a0.z += bfl(s0.y); a0.w += bfh(s0.y);
  a1.x += bfl(s1.x); a1.y += bfh(s1.x); a1.z += bfl(s1.y); a1.w += bfh(s1.y);
  float dv0 = rsqrtf((float)(cn0 + 1)), dv1 = rsqrtf((float)(cn1 + 1));
  a0.x *= dv0; a0.y *= dv0; a0.z *= dv0; a0.w *= dv0;
  a1.x *= dv1; a1.y *= dv1; a1.z *= dv1; a1.w *= dv1;
  float h0 = br, h1v = br;                    // epilogue gemms via broadcasts
  #pragma unroll
  for (int q2 = 0; q2 < 8; q2++){
    float4 w0, w1;
    w0.x = __shfl(a0.x, q2); w0.y = __shfl(a0.y, q2);
    w0.z = __shfl(a0.z, q2); w0.w = __shfl(a0.w, q2);
    w1.x = __shfl(a1.x, q2); w1.y = __shfl(a1.y, q2);
    w1.z = __shfl(a1.z, q2); w1.w = __shfl(a1.w, q2);
    h0 = fmaf(w0.x, wreg[q2*4+0], h0); h1v = fmaf(w1.x, wreg[q2*4+0], h1v);
    h0 = fmaf(w0.y, wreg[q2*4+1], h0); h1v = fmaf(w1.y, wreg[q2*4+1], h1v);
    h0 = fmaf(w0.z, wreg[q2*4+2], h0); h1v = fmaf(w1.z, wreg[q2*4+2], h1v);
    h0 = fmaf(w0.w, wreg[q2*4+3], h0); h1v = fmaf(w1.w, wreg[q2*4+3], h1v);
  }
  h[(size_t)v0*64 + lane] = f2bf(fmaxf(h0, 0.f));   // 128B coalesced
  if (has1) h[(size_t)v1*64 + lane] = f2bf(fmaxf(h1v, 0.f));
}

// K=64 GEMM (bf16 in) -> bf16 out, optional pre-scale by rsqrt(deg)
template<bool SCALE>
__global__ __launch_bounds__(256, 4) void k_gemm_b(const unsigned short* __restrict__ x,
                       const float* __restrict__ W, const int* __restrict__ cnt,
                       unsigned short* __restrict__ t, int n){
  int lane = threadIdx.x & 63;
  int gw = blockIdx.x*4 + uwave();
  int nw = gridDim.x*4;
  float wreg[64];
  #pragma unroll
  for (int k = 0; k < 64; k++) wreg[k] = W[k*64 + lane];
  for (int v = gw; v < n; v += nw){
    const uint4* xr = (const uint4*)(x + (size_t)v*64);   // uniform row, 8x16B
    float acc = 0.f;
    #pragma unroll
    for (int k8 = 0; k8 < 8; k8++){
      uint4 c = xr[k8];
      acc = fmaf(bfl(c.x), wreg[k8*8+0], acc);
      acc = fmaf(bfh(c.x), wreg[k8*8+1], acc);
      acc = fmaf(bfl(c.y), wreg[k8*8+2], acc);
      acc = fmaf(bfh(c.y), wreg[k8*8+3], acc);
      acc = fmaf(bfl(c.z), wreg[k8*8+4], acc);
      acc = fmaf(bfh(c.z), wreg[k8*8+5], acc);
      acc = fmaf(bfl(c.w), wreg[k8*8+6], acc);
      acc = fmaf(bfh(c.w), wreg[k8*8+7], acc);
    }
    if (SCALE) acc *= rsqrtf((float)(cnt[v] + 1));
    t[(size_t)v*64 + lane] = f2bf(acc);                    // 128B coalesced
  }
}

// K=64 GEMM (bf16 in) -> bf16 out + fused alpha_src/alpha_dst dots (f32 scores)
__global__ __launch_bounds__(256, 4) void k_gemm_alpha(const unsigned short* __restrict__ x,
                       const float* __restrict__ W,
                       const float* __restrict__ asrc, const float* __restrict__ adst,
                       unsigned short* __restrict__ t, float* __restrict__ als,
                       float* __restrict__ ald, int n){
  int lane = threadIdx.x & 63;
  int gw = blockIdx.x*4 + uwave();
  int nw = gridDim.x*4;
  float wreg[64];
  #pragma unroll
  for (int k = 0; k < 64; k++) wreg[k] = W[k*64 + lane];
  float asr = asrc[lane], adr = adst[lane];
  for (int v = gw; v < n; v += nw){
    const uint4* xr = (const uint4*)(x + (size_t)v*64);
    float acc = 0.f;
    #pragma unroll
    for (int k8 = 0; k8 < 8; k8++){
      uint4 c = xr[k8];
      acc = fmaf(bfl(c.x), wreg[k8*8+0], acc);
      acc = fmaf(bfh(c.x), wreg[k8*8+1], acc);
      acc = fmaf(bfl(c.y), wreg[k8*8+2], acc);
      acc = fmaf(bfh(c.y), wreg[k8*8+3], acc);
      acc = fmaf(bfl(c.z), wreg[k8*8+4], acc);
      acc = fmaf(bfh(c.z), wreg[k8*8+5], acc);
      acc = fmaf(bfl(c.w), wreg[k8*8+6], acc);
      acc = fmaf(bfh(c.w), wreg[k8*8+7], acc);
    }
    t[(size_t)v*64 + lane] = f2bf(acc);
    float s1 = acc * asr, s2 = acc * adr;
    #pragma unroll
    for (int off = 32; off; off >>= 1){
      s1 += __shfl_xor(s1, off);
      s2 += __shfl_xor(s2, off);
    }
    if (lane == 0){ als[v] = s1; ald[v] = s2; }
  }
}

// GCN agg (layer 3), DUAL-NODE bf16 rows in AND out.
__global__ __launch_bounds__(256) void k_gcn_agg(const unsigned short* __restrict__ t,
                          const int* __restrict__ adj, const int* __restrict__ cnt,
                          const float* __restrict__ b, unsigned short* __restrict__ h, int n){
  int lane = threadIdx.x & 63;
  int v0 = blockIdx.x*8 + uwave()*2;
  if (v0 >= n) return;                        // uniform
  int v1 = v0 + 1;
  bool has1 = v1 < n;
  if (!has1) v1 = v0;
  int cn0 = cnt[v0], cn1 = cnt[v1];
  int c0 = min(cn0, CAP), c1 = min(cn1, CAP);
  int ureg0 = n, ureg1 = n;                   // pad -> zero row
  if (lane < c0) ureg0 = (adj + (size_t)v0*CAP)[lane];
  if (lane < c1) ureg1 = (adj + (size_t)v1*CAP)[lane];
  int g = lane >> 3, q = lane & 7;
  float a0[8] = {0,0,0,0,0,0,0,0}, a1[8] = {0,0,0,0,0,0,0,0};
  int itm = (max(c0, c1) + 7) >> 3;
  #pragma unroll 2
  for (int jj = 0; jj < itm; jj++){
    int u0 = __shfl(ureg0, jj*8 + g);
    int u1 = __shfl(ureg1, jj*8 + g);
    uint4 r0 = ((const uint4*)(t + (size_t)u0*64))[q];    // both in flight
    uint4 r1 = ((const uint4*)(t + (size_t)u1*64))[q];
    a0[0] += bfl(r0.x); a0[1] += bfh(r0.x); a0[2] += bfl(r0.y); a0[3] += bfh(r0.y);
    a0[4] += bfl(r0.z); a0[5] += bfh(r0.z); a0[6] += bfl(r0.w); a0[7] += bfh(r0.w);
    a1[0] += bfl(r1.x); a1[1] += bfh(r1.x); a1[2] += bfl(r1.y); a1[3] += bfh(r1.y);
    a1[4] += bfl(r1.z); a1[5] += bfh(r1.z); a1[6] += bfl(r1.w); a1[7] += bfh(r1.w);
  }
  #pragma unroll
  for (int off = 8; off <= 32; off <<= 1){
    #pragma unroll
    for (int k = 0; k < 8; k++){
      a0[k] += __shfl_xor(a0[k], off);
      a1[k] += __shfl_xor(a1[k], off);
    }
  }
  uint4 s0 = ((const uint4*)(t + (size_t)v0*64))[q];      // self rows (L2-hot)
  uint4 s1 = ((const uint4*)(t + (size_t)v1*64))[q];
  a0[0] += bfl(s0.x); a0[1] += bfh(s0.x); a0[2] += bfl(s0.y); a0[3] += bfh(s0.y);
  a0[4] += bfl(s0.z); a0[5] += bfh(s0.z); a0[6] += bfl(s0.w); a0[7] += bfh(s0.w);
  a1[0] += bfl(s1.x); a1[1] += bfh(s1.x); a1[2] += bfl(s1.y); a1[3] += bfh(s1.y);
  a1[4] += bfl(s1.z); a1[5] += bfh(s1.z); a1[6] += bfl(s1.w); a1[7] += bfh(s1.w);
  float dv0 = rsqrtf((float)(cn0 + 1)), dv1 = rsqrtf((float)(cn1 + 1));
  float4 b0 = ((const float4*)b)[2*q], b1v = ((const float4*)b)[2*q+1];
  if (g == 0){
    float r0 = fmaxf(fmaf(a0[0], dv0, b0.x), 0.f),  r1 = fmaxf(fmaf(a0[1], dv0, b0.y), 0.f);
    float r2 = fmaxf(fmaf(a0[2], dv0, b0.z), 0.f),  r3 = fmaxf(fmaf(a0[3], dv0, b0.w), 0.f);
    float r4 = fmaxf(fmaf(a0[4], dv0, b1v.x), 0.f), r5 = fmaxf(fmaf(a0[5], dv0, b1v.y), 0.f);
    float r6 = fmaxf(fmaf(a0[6], dv0, b1v.z), 0.f), r7 = fmaxf(fmaf(a0[7], dv0, b1v.w), 0.f);
    uint4 o;
    o.x = (unsigned)f2bf(r0) | ((unsigned)f2bf(r1) << 16);
    o.y = (unsigned)f2bf(r2) | ((unsigned)f2bf(r3) << 16);
    o.z = (unsigned)f2bf(r4) | ((unsigned)f2bf(r5) << 16);
    o.w = (unsigned)f2bf(r6) | ((unsigned)f2bf(r7) << 16);
    ((uint4*)(h + (size_t)v0*64))[q] = o;                 // 128B store
  } else if (g == 1 && has1){
    float r0 = fmaxf(fmaf(a1[0], dv1, b0.x), 0.f),  r1 = fmaxf(fmaf(a1[1], dv1, b0.y), 0.f);
    float r2 = fmaxf(fmaf(a1[2], dv1, b0.z), 0.f),  r3 = fmaxf(fmaf(a1[3], dv1, b0.w), 0.f);
    float r4 = fmaxf(fmaf(a1[4], dv1, b1v.x), 0.f), r5 = fmaxf(fmaf(a1[5], dv1, b1v.y), 0.f);
    float r6 = fmaxf(fmaf(a1[6], dv1, b1v.z), 0.f), r7 = fmaxf(fmaf(a1[7], dv1, b1v.w), 0.f);
    uint4 o;
    o.x = (unsigned)f2bf(r0) | ((unsigned)f2bf(r1) << 16);
    o.y = (unsigned)f2bf(r2) | ((unsigned)f2bf(r3) << 16);
    o.z = (unsigned)f2bf(r4) | ((unsigned)f2bf(r5) << 16);
    o.w = (unsigned)f2bf(r6) | ((unsigned)f2bf(r7) << 16);
    ((uint4*)(h + (size_t)v1*64))[q] = o;
  }
}

// GAT agg, DUAL-NODE bf16 rows in AND out: 2 softmaxes + interleaved gathers.
__global__ __launch_bounds__(256) void k_gat_agg(const unsigned short* __restrict__ t,
                          const int* __restrict__ adj, const int* __restrict__ cnt,
                          const float* __restrict__ als, const float* __restrict__ ald,
                          const float* __restrict__ b, unsigned short* __restrict__ h, int n){
  int lane = threadIdx.x & 63;
  int v0 = blockIdx.x*8 + uwave()*2;
  if (v0 >= n) return;
  int v1 = v0 + 1;
  bool has1 = v1 < n;
  if (!has1) v1 = v0;
  int c0 = min(cnt[v0], CAP), c1 = min(cnt[v1], CAP);
  int ureg0 = n, ureg1 = n;                   // pad -> zero row
  if (lane < c0) ureg0 = (adj + (size_t)v0*CAP)[lane];
  if (lane < c1) ureg1 = (adj + (size_t)v1*CAP)[lane];
  int us0 = (lane < c0) ? ureg0 : v0;
  int us1 = (lane < c1) ? ureg1 : v1;
  float adv0 = ald[v0], adv1 = ald[v1];       // uniform
  float e0 = als[us0] + adv0;                 // both gathers in flight
  float e1 = als[us1] + adv1;
  e0 = e0 > 0.f ? e0 : 0.2f*e0;
  e1 = e1 > 0.f ? e1 : 0.2f*e1;
  float es0 = als[v0] + adv0; es0 = es0 > 0.f ? es0 : 0.2f*es0;
  float es1 = als[v1] + adv1; es1 = es1 > 0.f ? es1 : 0.2f*es1;
  float em0 = (lane < c0) ? e0 : -1e30f;
  float em1 = (lane < c1) ? e1 : -1e30f;
  #pragma unroll
  for (int off = 32; off; off >>= 1){
    em0 = fmaxf(em0, __shfl_xor(em0, off));
    em1 = fmaxf(em1, __shfl_xor(em1, off));
  }
  em0 = fmaxf(em0, es0); em1 = fmaxf(em1, es1);
  float p0 = (lane < c0) ? __expf(e0 - em0) : 0.f;
  float p1 = (lane < c1) ? __expf(e1 - em1) : 0.f;
  float sm0 = p0, sm1 = p1;
  #pragma unroll
  for (int off = 32; off; off >>= 1){
    sm0 += __shfl_xor(sm0, off);
    sm1 += __shfl_xor(sm1, off);
  }
  float ps0 = __expf(es0 - em0), ps1 = __expf(es1 - em1);
  float inv0 = 1.f / (sm0 + ps0), inv1 = 1.f / (sm1 + ps1);
  int g = lane >> 3, q = lane & 7;
  float a0[8] = {0,0,0,0,0,0,0,0}, a1[8] = {0,0,0,0,0,0,0,0};
  int itm = (max(c0, c1) + 7) >> 3;
  #pragma unroll 2
  for (int jj = 0; jj < itm; jj++){
    int   u0 = __shfl(ureg0, jj*8 + g);
    int   u1 = __shfl(ureg1, jj*8 + g);
    float w0 = __shfl(p0,    jj*8 + g);       // pad slots p=0
    float w1 = __shfl(p1,    jj*8 + g);
    uint4 r0 = ((const uint4*)(t + (size_t)u0*64))[q];
    uint4 r1 = ((const uint4*)(t + (size_t)u1*64))[q];
    a0[0] = fmaf(w0, bfl(r0.x), a0[0]); a0[1] = fmaf(w0, bfh(r0.x), a0[1]);
    a0[2] = fmaf(w0, bfl(r0.y), a0[2]); a0[3] = fmaf(w0, bfh(r0.y), a0[3]);
    a0[4] = fmaf(w0, bfl(r0.z), a0[4]); a0[5] = fmaf(w0, bfh(r0.z), a0[5]);
    a0[6] = fmaf(w0, bfl(r0.w), a0[6]); a0[7] = fmaf(w0, bfh(r0.w), a0[7]);
    a1[0] = fmaf(w1, bfl(r1.x), a1[0]); a1[1] = fmaf(w1, bfh(r1.x), a1[1]);
    a1[2] = fmaf(w1, bfl(r1.y), a1[2]); a1[3] = fmaf(w1, bfh(r1.y), a1[3]);
    a1[4] = fmaf(w1, bfl(r1.z), a1[4]); a1[5] = fmaf(w1, bfh(r1.z), a1[5]);
    a1[6] = fmaf(w1, bfl(r1.w), a1[6]); a1[7] = fmaf(w1, bfh(r1.w), a1[7]);
  }
  #pragma unroll
  for (int off = 8; off <= 32; off <<= 1){
    #pragma unroll
    for (int k = 0; k < 8; k++){
      a0[k] += __shfl_xor(a0[k], off);
      a1[k] += __shfl_xor(a1[k], off);
    }
  }
  uint4 s0 = ((const uint4*)(t + (size_t)v0*64))[q];      // self rows
  uint4 s1 = ((const uint4*)(t + (size_t)v1*64))[q];
  a0[0] = fmaf(ps0, bfl(s0.x), a0[0]); a0[1] = fmaf(ps0, bfh(s0.x), a0[1]);
  a0[2] = fmaf(ps0, bfl(s0.y), a0[2]); a0[3] = fmaf(ps0, bfh(s0.y), a0[3]);
  a0[4] = fmaf(ps0, bfl(s0.z), a0[4]); a0[5] = fmaf(ps0, bfh(s0.z), a0[5]);
  a0[6] = fmaf(ps0, bfl(s0.w), a0[6]); a0[7] = fmaf(ps0, bfh(s0.w), a0[7]);
  a1[0] = fmaf(ps1, bfl(s1.x), a1[0]); a1[1] = fmaf(ps1, bfh(s1.x), a1[1]);
  a1[2] = fmaf(ps1, bfl(s1.y), a1[2]); a1[3] = fmaf(ps1, bfh(s1.y), a1[3]);
  a1[4] = fmaf(ps1, bfl(s1.z), a1[4]); a1[5] = fmaf(ps1, bfh(s1.z), a1[5]);
  a1[6] = fmaf(ps1, bfl(s1.w), a1[6]); a1[7] = fmaf(ps1, bfh(s1.w), a1[7]);
  float4 b0 = ((const float4*)b)[2*q], b1v = ((const float4*)b)[2*q+1];
  if (g == 0){
    float r0 = fmaxf(fmaf(a0[0], inv0, b0.x), 0.f),  r1 = fmaxf(fmaf(a0[1], inv0, b0.y), 0.f);
    float r2 = fmaxf(fmaf(a0[2], inv0, b0.z), 0.f),  r3 = fmaxf(fmaf(a0[3], inv0, b0.w), 0.f);
    float r4 = fmaxf(fmaf(a0[4], inv0, b1v.x), 0.f), r5 = fmaxf(fmaf(a0[5], inv0, b1v.y), 0.f);
    float r6 = fmaxf(fmaf(a0[6], inv0, b1v.z), 0.f), r7 = fmaxf(fmaf(a0[7], inv0, b1v.w), 0.f);
    uint4 o;
    o.x = (unsigned)f2bf(r0) | ((unsigned)f2bf(r1) << 16);
    o.y = (unsigned)f2bf(r2) | ((unsigned)f2bf(r3) << 16);
    o.z = (unsigned)f2bf(r4) | ((unsigned)f2bf(r5) << 16);
    o.w = (unsigned)f2bf(r6) | ((unsigned)f2bf(r7) << 16);
    ((uint4*)(h + (size_t)v0*64))[q] = o;
  } else if (g == 1 && has1){
    float r0 = fmaxf(fmaf(a1[0], inv1, b0.x), 0.f),  r1 = fmaxf(fmaf(a1[1], inv1, b0.y), 0.f);
    float r2 = fmaxf(fmaf(a1[2], inv1, b0.z), 0.f),  r3 = fmaxf(fmaf(a1[3], inv1, b0.w), 0.f);
    float r4 = fmaxf(fmaf(a1[4], inv1, b1v.x), 0.f), r5 = fmaxf(fmaf(a1[5], inv1, b1v.y), 0.f);
    float r6 = fmaxf(fmaf(a1[6], inv1, b1v.z), 0.f), r7 = fmaxf(fmaf(a1[7], inv1, b1v.w), 0.f);
    uint4 o;
    o.x = (unsigned)f2bf(r0) | ((unsigned)f2bf(r1) << 16);
    o.y = (unsigned)f2bf(r2) | ((unsigned)f2bf(r3) << 16);
    o.z = (unsigned)f2bf(r4) | ((unsigned)f2bf(r5) << 16);
    o.w = (unsigned)f2bf(r6) | ((unsigned)f2bf(r7) << 16);
    ((uint4*)(h + (size_t)v1*64))[q] = o;
  }
}

// heads: gemm_alpha-mirror structure (dense Wcat/bcat, resident wreg[64]), bf16 h.
__global__ __launch_bounds__(256, 4) void k_heads(const unsigned short* __restrict__ h,
                        const float* __restrict__ Wcat, const float* __restrict__ bcat,
                        const float* __restrict__ Wb2, const float* __restrict__ bb2,
                        float* __restrict__ out_opt, float* __restrict__ out_bot, int n){
  int lane = threadIdx.x & 63;
  int gw = blockIdx.x*4 + uwave();
  int nw = gridDim.x*4;
  float wreg[64];
  #pragma unroll
  for (int k = 0; k < 64; k++) wreg[k] = Wcat[k*64 + lane];
  float bcr  = bcat[lane];
  float wb2r = (lane >= 32) ? Wb2[lane-32] : 0.f;
  float bb2r = bb2[0];
  for (int v = gw; v < n; v += nw){
    const uint4* xr = (const uint4*)(h + (size_t)v*64);   // uniform row, 8x16B
    float acc = bcr;
    #pragma unroll
    for (int k8 = 0; k8 < 8; k8++){
      uint4 c = xr[k8];
      acc = fmaf(bfl(c.x), wreg[k8*8+0], acc);
      acc = fmaf(bfh(c.x), wreg[k8*8+1], acc);
      acc = fmaf(bfl(c.y), wreg[k8*8+2], acc);
      acc = fmaf(bfh(c.y), wreg[k8*8+3], acc);
      acc = fmaf(bfl(c.z), wreg[k8*8+4], acc);
      acc = fmaf(bfh(c.z), wreg[k8*8+5], acc);
      acc = fmaf(bfl(c.w), wreg[k8*8+6], acc);
      acc = fmaf(bfh(c.w), wreg[k8*8+7], acc);
    }
    if (lane < 10) out_opt[(size_t)v*10 + lane] = acc;
    float contrib = fmaxf(acc, 0.f) * wb2r;   // 0 for lanes<32
    #pragma unroll
    for (int off = 32; off; off >>= 1) contrib += __shfl_xor(contrib, off);
    if (lane == 0) out_bot[v] = 1.f / (1.f + __expf(-(contrib + bb2r)));
  }
}

// mean embedding partials over bf16 h: block-reduce, 64-addr atomics
__global__ __launch_bounds__(256) void k_mean(const unsigned short* __restrict__ h,
                       float* __restrict__ emb_acc, int n){
  __shared__ float red[256];
  int tid = threadIdx.x;
  int w = tid >> 6, lane = tid & 63;
  float s = 0.f;
  for (int r = blockIdx.x*4 + w; r < n; r += 1024)
    s += __uint_as_float(((unsigned)h[(size_t)r*64 + lane]) << 16);
  red[tid] = s;
  __syncthreads();
  if (tid < 64)
    atomicAdd(&emb_acc[tid], red[tid] + red[64+tid] + red[128+tid] + red[192+tid]);
}

__global__ void k_embed(const float* __restrict__ emb_acc, float* __restrict__ out_emb,
                        float invn){
  if (threadIdx.x < 64) out_emb[threadIdx.x] = emb_acc[threadIdx.x] * invn;
}

extern "C" void kernel_launch(void* const* d_in, const int* in_sizes, int n_in,
                              void* d_out, int out_size, void* d_ws, size_t ws_size,
                              hipStream_t stream) {
  const float* x    = (const float*)d_in[0];
  const int*   ei   = (const int*)d_in[1];
  const float* W1   = (const float*)d_in[2];
  const float* b1   = (const float*)d_in[3];
  const float* W2   = (const float*)d_in[4];
  const float* a_s  = (const float*)d_in[5];
  const float* a_d  = (const float*)d_in[6];
  const float* b2   = (const float*)d_in[7];
  const float* W3   = (const float*)d_in[8];
  const float* b3   = (const float*)d_in[9];
  const float* Wopt = (const float*)d_in[10];
  const float* bopt = (const float*)d_in[11];
  const float* Wb1  = (const float*)d_in[12];
  const float* bb1  = (const float*)d_in[13];
  const float* Wb2  = (const float*)d_in[14];
  const float* bb2  = (const float*)d_in[15];

  int n = in_sizes[0] / 32;      // 100000
  int e = in_sizes[1] / 2;       // 1250000
  const int* src = ei;
  const int* dst = ei + e;

  char* ws = (char*)d_ws;
  size_t off = 0;
  auto alloc = [&](size_t bytes) -> void* {
    void* p = ws + off;
    off += (bytes + 255) & ~(size_t)255;
    return p;
  };
  int*            cnt     = (int*)           alloc((size_t)n * 4);
  int*            adj     = (int*)           alloc((size_t)n * CAP * 4);
  float*          als     = (float*)         alloc((size_t)n * 4);
  float*          ald     = (float*)         alloc((size_t)n * 4);
  unsigned short* xh      = (unsigned short*)alloc((size_t)(n+1) * 32 * 2); // +zero row
  unsigned short* tb      = (unsigned short*)alloc((size_t)(n+1) * 64 * 2); // +zero row
  unsigned short* hbuf    = (unsigned short*)alloc((size_t)n * 64 * 2);     // bf16 h
  float*          emb_acc = (float*)         alloc((size_t)64 * 4);
  float*          Wcat    = (float*)         alloc((size_t)4096 * 4);
  float*          bcat    = (float*)         alloc((size_t)64 * 4);
  int*            bcnt    = (int*)           alloc((size_t)NBUK * 4);

  // pairs buffer overlays hbuf (hbuf first written by k_agg32g, after hist)
  int pbcap = e / NBUK + 8192;   // mean + 22 sigma; NBUK*pbcap*8 <= n*128
  uint2* pairs = (uint2*)hbuf;

  float* out_opt = (float*)d_out;
  float* out_bot = out_opt + (size_t)n * 10;
  float* out_emb = out_bot + n;

  int nb8    = (n + 7) / 8;
  int nbN    = (n + 255) / 256;
  int nbP    = (e + 1023) / 1024;  // k_part: 1024 edges/block
  int total4 = n*32/4;
  int nbC    = (total4 + 255) / 256;

  k_setup<<<nbN, 256, 0, stream>>>(Wopt, bopt, Wb1, bb1, Wcat, bcat,
                                   cnt, bcnt, tb, xh, emb_acc, n);
  k_part<<<nbP, 256, 0, stream>>>(src, dst, pairs, bcnt, e, pbcap, 8.0f/(float)n);
  k_fill<<<2048, 256, 0, stream>>>(pairs, bcnt, cnt, adj, pbcap);
  k_castscale<<<nbC, 256, 0, stream>>>(x, cnt, xh, total4);

  // layer 1: GCN(32->64) fully fused: dual-node gather + epilogue gemm -> h1 (bf16)
  k_agg32g<<<nb8, 256, 0, stream>>>(xh, adj, cnt, W1, b1, hbuf, n);

  // layer 2: GAT(64->64): gemm -> bf16 t2 + scores, dual-node softmax-gather -> h2
  k_gemm_alpha<<<1024, 256, 0, stream>>>(hbuf, W2, a_s, a_d, tb, als, ald, n);
  k_gat_agg<<<nb8, 256, 0, stream>>>(tb, adj, cnt, als, ald, b2, hbuf, n);

  // layer 3: GCN(64->64): gemm (pre-scaled) -> bf16 t3, dual-node gather -> h3
  k_gemm_b<true><<<1024, 256, 0, stream>>>(hbuf, W3, cnt, tb, n);
  k_gcn_agg<<<nb8, 256, 0, stream>>>(tb, adj, cnt, b3, hbuf, n);

  // heads, mean, final scale
  k_heads<<<1024, 256, 0, stream>>>(hbuf, Wcat, bcat, Wb2, bb2,
                                    out_opt, out_bot, n);
  k_mean<<<256, 256, 0, stream>>>(hbuf, emb_acc, n);
  k_embed<<<1, 64, 0, stream>>>(emb_acc, out_emb, 1.0f / (float)n);
}

// Round 3
// 377.329 us; speedup vs baseline: 1.0950x; 1.0950x over previous
//
#include <hip/hip_runtime.h>
#include <hip/hip_bf16.h>

// WorkflowGNN: GCN(32->64)+ReLU, GAT(64->64,h=1)+ReLU, GCN(64->64)+ReLU,
// heads: opt [N,10], bottleneck [N,1], mean-embed [64]. f32 in/out.
// R19: adjacency build without ANY global atomics. R18's k_fill (~55us) was
// transaction-bound on 1.25M returning global atomicAdds (locality didn't
// matter). Now: k_part bins edges into 782 EXACT buckets (dst>>7, 128 nodes
// each; LDS-aggregated cursors, pair writes hit a ~100KB L2-resident cursor
// frontier), then k_fill = one block per bucket, builds adj rows in LDS
// (32KB tile, LDS atomics only) and writes rows + cnt fully coalesced.
// adj slots beyond cnt are garbage -> never read (lane<c guards).

#define CAP 64
#define NP2 128          // nodes per bucket (LDS tile rows), = 1<<7
#define NB2MAX 800       // LDS cursor array bound (n <= 102400)

__device__ __forceinline__ int uwave(){                 // wave id, known-uniform
  return __builtin_amdgcn_readfirstlane(threadIdx.x >> 6);
}
__device__ __forceinline__ unsigned short f2bf(float f){ // RNE, finite inputs
  unsigned u = __float_as_uint(f);
  return (unsigned short)((u + 0x7fffu + ((u >> 16) & 1u)) >> 16);
}
__device__ __forceinline__ float bfl(unsigned u){ return __uint_as_float(u << 16); }
__device__ __forceinline__ float bfh(unsigned u){ return __uint_as_float(u & 0xffff0000u); }

// setup: zero bcnt/pad-rows/emb_acc, pack Wcat/bcat (cnt now written by k_fill)
__global__ void k_setup(const float* __restrict__ Wopt, const float* __restrict__ bopt,
                        const float* __restrict__ Wb1, const float* __restrict__ bb1,
                        float* __restrict__ Wcat, float* __restrict__ bcat,
                        int* __restrict__ bcnt, unsigned short* __restrict__ tb,
                        unsigned short* __restrict__ xh, float* __restrict__ emb_acc,
                        int n, int nb2){
  int i = blockIdx.x*blockDim.x + threadIdx.x;
  if (i < nb2) bcnt[i] = 0;
  if (blockIdx.x == 0){
    int tid = threadIdx.x;
    for (int j = tid; j < 4096; j += 256){    // pack head weights
      int f = j >> 6, c = j & 63;
      float w = 0.f;
      if (c < 10)       w = Wopt[f*10 + c];
      else if (c >= 32) w = Wb1[f*32 + (c-32)];
      Wcat[j] = w;
    }
    if (tid < 64){
      float b = 0.f;
      if (tid < 10)       b = bopt[tid];
      else if (tid >= 32) b = bb1[tid-32];
      bcat[tid] = b;
      tb[(size_t)n*64 + tid] = 0;             // zero pad row (64-feat)
      emb_acc[tid] = 0.f;
    }
    if (tid >= 64 && tid < 96) xh[(size_t)n*32 + (tid-64)] = 0;  // zero pad row (32-feat)
  }
}

// pass A: bin edges into exact dst-range buckets (bk = dst>>7). One coalesced
// read of src/dst (2x int4 each), LDS-aggregated cursors -> ~nb2 global
// atomics per block on 782 hot counters. Writes land on the L2-resident
// cursor frontier (~100KB) -> merge before HBM.
__global__ __launch_bounds__(256) void k_part(const int* __restrict__ src,
                        const int* __restrict__ dst,
                        uint2* __restrict__ pairs, int* __restrict__ bcnt,
                        int e, int nb2, int pbcap){
  __shared__ int lcnt[NB2MAX];
  __shared__ int lbase[NB2MAX];
  int tid = threadIdx.x;
  for (int j = tid; j < nb2; j += 256) lcnt[j] = 0;
  __syncthreads();
  int i0 = blockIdx.x*2048 + tid*8;
  int d[8], s[8], bk[8], lp[8];
  int nv = e - i0;
  if (nv > 8) nv = 8;
  if (nv < 0) nv = 0;
  if (nv == 8){
    int4 d0 = *(const int4*)(dst + i0), d1 = *(const int4*)(dst + i0 + 4);
    int4 s0 = *(const int4*)(src + i0), s1 = *(const int4*)(src + i0 + 4);
    d[0]=d0.x; d[1]=d0.y; d[2]=d0.z; d[3]=d0.w;
    d[4]=d1.x; d[5]=d1.y; d[6]=d1.z; d[7]=d1.w;
    s[0]=s0.x; s[1]=s0.y; s[2]=s0.z; s[3]=s0.w;
    s[4]=s1.x; s[5]=s1.y; s[6]=s1.z; s[7]=s1.w;
  } else {
    #pragma unroll
    for (int j = 0; j < 8; j++){ d[j] = 0; s[j] = 0; }
    for (int j = 0; j < nv; j++){ d[j] = dst[i0+j]; s[j] = src[i0+j]; }
  }
  #pragma unroll
  for (int j = 0; j < 8; j++){
    if (j < nv){
      bk[j] = d[j] >> 7;                      // exact: bucket owns [bk*128, bk*128+128)
      lp[j] = atomicAdd(&lcnt[bk[j]], 1);
    }
  }
  __syncthreads();
  for (int j = tid; j < nb2; j += 256){
    int c = lcnt[j];
    if (c) lbase[j] = atomicAdd(&bcnt[j], c);
  }
  __syncthreads();
  #pragma unroll
  for (int j = 0; j < 8; j++){
    if (j < nv){
      int p = lbase[bk[j]] + lp[j];
      if (p < pbcap)
        pairs[(size_t)bk[j]*pbcap + p] = make_uint2((unsigned)d[j], (unsigned)s[j]);
    }
  }
}

// pass B: one block per bucket. Build 128 adj rows in LDS (LDS atomics only,
// zero global atomics), then write rows + cnt fully coalesced. Slots beyond
// lc[r] are garbage -> never read downstream (lane < c guards).
__global__ __launch_bounds__(256) void k_fill(const uint2* __restrict__ pairs,
                        const int* __restrict__ bcnt, int* __restrict__ cnt,
                        int* __restrict__ adj, int pbcap, int n){
  __shared__ int lc[NP2];
  __shared__ int ladj[NP2*CAP];               // 32KB
  int b = blockIdx.x;
  int lo = b << 7;
  int nn = min(NP2, n - lo);
  int tid = threadIdx.x;
  for (int j = tid; j < NP2; j += 256) lc[j] = 0;
  __syncthreads();
  int m = bcnt[b];
  if (m > pbcap) m = pbcap;
  const uint2* pb = pairs + (size_t)b*pbcap;
  for (int j = tid; j < m; j += 256){
    uint2 p = pb[j];
    int r = (int)p.x - lo;
    int pos = atomicAdd(&lc[r], 1);
    if (pos < CAP) ladj[(r << 6) + pos] = (int)p.y;
  }
  __syncthreads();
  if (tid < nn) cnt[lo + tid] = lc[tid];
  int tot = nn << 4;                          // nn*64 ints / 4 per uint4
  uint4* ga = (uint4*)(adj + (size_t)lo*CAP);
  const uint4* la = (const uint4*)ladj;
  for (int j = tid; j < tot; j += 256) ga[j] = la[j];
}

// cast x -> bf16, pre-scaled by rsqrt(deg): xs[v] = x[v]*rsqrt(cnt[v]+1)
__global__ void k_castscale(const float* __restrict__ x, const int* __restrict__ cnt,
                            unsigned short* __restrict__ xh, int total4){
  int i = blockIdx.x*blockDim.x + threadIdx.x;
  if (i >= total4) return;
  int row = i >> 3;                           // 8 float4 per 32-elem row
  float dv = rsqrtf((float)(cnt[row] + 1));
  float4 v = ((const float4*)x)[i];
  uint2 o;
  o.x = (unsigned)f2bf(v.x*dv) | ((unsigned)f2bf(v.y*dv) << 16);
  o.y = (unsigned)f2bf(v.z*dv) | ((unsigned)f2bf(v.w*dv) << 16);
  ((uint2*)xh)[i] = o;
}

// layer-1 FUSED aggregate+gemm, DUAL-NODE, bf16 out.
__global__ __launch_bounds__(256) void k_agg32g(const unsigned short* __restrict__ xh,
                          const int* __restrict__ adj, const int* __restrict__ cnt,
                          const float* __restrict__ W1, const float* __restrict__ b1,
                          unsigned short* __restrict__ h, int n){
  int lane = threadIdx.x & 63;
  float wreg[32];
  #pragma unroll
  for (int k = 0; k < 32; k++) wreg[k] = W1[k*64 + lane];  // coalesced, once
  float br = b1[lane];
  int v0 = blockIdx.x*8 + uwave()*2;
  if (v0 >= n) return;                        // uniform
  int v1 = v0 + 1;
  bool has1 = v1 < n;
  if (!has1) v1 = v0;
  int cn0 = cnt[v0], cn1 = cnt[v1];
  int c0 = min(cn0, CAP), c1 = min(cn1, CAP);
  int ureg0 = n, ureg1 = n;                   // pad -> zero row
  if (lane < c0) ureg0 = (adj + (size_t)v0*CAP)[lane];
  if (lane < c1) ureg1 = (adj + (size_t)v1*CAP)[lane];
  int g = lane >> 3, q = lane & 7;
  float4 a0 = {0.f,0.f,0.f,0.f}, a1 = {0.f,0.f,0.f,0.f};
  int itm = (max(c0, c1) + 7) >> 3;
  #pragma unroll 2
  for (int jj = 0; jj < itm; jj++){
    int u0 = __shfl(ureg0, jj*8 + g);         // pad iters -> zero row (L1-hot)
    int u1 = __shfl(ureg1, jj*8 + g);
    uint2 r0 = ((const uint2*)(xh + (size_t)u0*32))[q];   // both loads in flight
    uint2 r1 = ((const uint2*)(xh + (size_t)u1*32))[q];
    a0.x += bfl(r0.x); a0.y += bfh(r0.x); a0.z += bfl(r0.y); a0.w += bfh(r0.y);
    a1.x += bfl(r1.x); a1.y += bfh(r1.x); a1.z += bfl(r1.y); a1.w += bfh(r1.y);
  }
  #pragma unroll
  for (int off = 8; off <= 32; off <<= 1){
    a0.x += __shfl_xor(a0.x, off); a0.y += __shfl_xor(a0.y, off);
    a0.z += __shfl_xor(a0.z, off); a0.w += __shfl_xor(a0.w, off);
    a1.x += __shfl_xor(a1.x, off); a1.y += __shfl_xor(a1.y, off);
    a1.z += __shfl_xor(a1.z, off); a1.w += __shfl_xor(a1.w, off);
  }
  uint2 s0 = ((const uint2*)(xh + (size_t)v0*32))[q];     // self rows (pre-scaled)
  uint2 s1 = ((const uint2*)(xh + (size_t)v1*32))[q];
  a0.x += bfl(s0.x); a0.y += bfh(s0.x); a0.z += bfl(s0.y); a0.w += bfh(s0.y);
  a1.x += bfl(s1.x); a1.y += bfh(s1.x); a1.z += bfl(s1.y); a1.w += bfh(s1.y);
  float dv0 = rsqrtf((float)(cn0 + 1)), dv1 = rsqrtf((float)(cn1 + 1));
  a0.x *= dv0; a0.y *= dv0; a0.z *= dv0; a0.w *= dv0;
  a1.x *= dv1; a1.y *= dv1; a1.z *= dv1; a1.w *= dv1;
  float h0 = br, h1v = br;                    // epilogue gemms via broadcasts
  #pragma unroll
  for (int q2 = 0; q2 < 8; q2++){
    float4 w0, w1;
    w0.x = __shfl(a0.x, q2); w0.y = __shfl(a0.y, q2);
    w0.z = __shfl(a0.z, q2); w0.w = __shfl(a0.w, q2);
    w1.x = __shfl(a1.x, q2); w1.y = __shfl(a1.y, q2);
    w1.z = __shfl(a1.z, q2); w1.w = __shfl(a1.w, q2);
    h0 = fmaf(w0.x, wreg[q2*4+0], h0); h1v = fmaf(w1.x, wreg[q2*4+0], h1v);
    h0 = fmaf(w0.y, wreg[q2*4+1], h0); h1v = fmaf(w1.y, wreg[q2*4+1], h1v);
    h0 = fmaf(w0.z, wreg[q2*4+2], h0); h1v = fmaf(w1.z, wreg[q2*4+2], h1v);
    h0 = fmaf(w0.w, wreg[q2*4+3], h0); h1v = fmaf(w1.w, wreg[q2*4+3], h1v);
  }
  h[(size_t)v0*64 + lane] = f2bf(fmaxf(h0, 0.f));   // 128B coalesced
  if (has1) h[(size_t)v1*64 + lane] = f2bf(fmaxf(h1v, 0.f));
}

// K=64 GEMM (bf16 in) -> bf16 out, optional pre-scale by rsqrt(deg)
template<bool SCALE>
__global__ __launch_bounds__(256, 4) void k_gemm_b(const unsigned short* __restrict__ x,
                       const float* __restrict__ W, const int* __restrict__ cnt,
                       unsigned short* __restrict__ t, int n){
  int lane = threadIdx.x & 63;
  int gw = blockIdx.x*4 + uwave();
  int nw = gridDim.x*4;
  float wreg[64];
  #pragma unroll
  for (int k = 0; k < 64; k++) wreg[k] = W[k*64 + lane];
  for (int v = gw; v < n; v += nw){
    const uint4* xr = (const uint4*)(x + (size_t)v*64);   // uniform row, 8x16B
    float acc = 0.f;
    #pragma unroll
    for (int k8 = 0; k8 < 8; k8++){
      uint4 c = xr[k8];
      acc = fmaf(bfl(c.x), wreg[k8*8+0], acc);
      acc = fmaf(bfh(c.x), wreg[k8*8+1], acc);
      acc = fmaf(bfl(c.y), wreg[k8*8+2], acc);
      acc = fmaf(bfh(c.y), wreg[k8*8+3], acc);
      acc = fmaf(bfl(c.z), wreg[k8*8+4], acc);
      acc = fmaf(bfh(c.z), wreg[k8*8+5], acc);
      acc = fmaf(bfl(c.w), wreg[k8*8+6], acc);
      acc = fmaf(bfh(c.w), wreg[k8*8+7], acc);
    }
    if (SCALE) acc *= rsqrtf((float)(cnt[v] + 1));
    t[(size_t)v*64 + lane] = f2bf(acc);                    // 128B coalesced
  }
}

// K=64 GEMM (bf16 in) -> bf16 out + fused alpha_src/alpha_dst dots (f32 scores)
__global__ __launch_bounds__(256, 4) void k_gemm_alpha(const unsigned short* __restrict__ x,
                       const float* __restrict__ W,
                       const float* __restrict__ asrc, const float* __restrict__ adst,
                       unsigned short* __restrict__ t, float* __restrict__ als,
                       float* __restrict__ ald, int n){
  int lane = threadIdx.x & 63;
  int gw = blockIdx.x*4 + uwave();
  int nw = gridDim.x*4;
  float wreg[64];
  #pragma unroll
  for (int k = 0; k < 64; k++) wreg[k] = W[k*64 + lane];
  float asr = asrc[lane], adr = adst[lane];
  for (int v = gw; v < n; v += nw){
    const uint4* xr = (const uint4*)(x + (size_t)v*64);
    float acc = 0.f;
    #pragma unroll
    for (int k8 = 0; k8 < 8; k8++){
      uint4 c = xr[k8];
      acc = fmaf(bfl(c.x), wreg[k8*8+0], acc);
      acc = fmaf(bfh(c.x), wreg[k8*8+1], acc);
      acc = fmaf(bfl(c.y), wreg[k8*8+2], acc);
      acc = fmaf(bfh(c.y), wreg[k8*8+3], acc);
      acc = fmaf(bfl(c.z), wreg[k8*8+4], acc);
      acc = fmaf(bfh(c.z), wreg[k8*8+5], acc);
      acc = fmaf(bfl(c.w), wreg[k8*8+6], acc);
      acc = fmaf(bfh(c.w), wreg[k8*8+7], acc);
    }
    t[(size_t)v*64 + lane] = f2bf(acc);
    float s1 = acc * asr, s2 = acc * adr;
    #pragma unroll
    for (int off = 32; off; off >>= 1){
      s1 += __shfl_xor(s1, off);
      s2 += __shfl_xor(s2, off);
    }
    if (lane == 0){ als[v] = s1; ald[v] = s2; }
  }
}

// GCN agg (layer 3), DUAL-NODE bf16 rows in AND out.
__global__ __launch_bounds__(256) void k_gcn_agg(const unsigned short* __restrict__ t,
                          const int* __restrict__ adj, const int* __restrict__ cnt,
                          const float* __restrict__ b, unsigned short* __restrict__ h, int n){
  int lane = threadIdx.x & 63;
  int v0 = blockIdx.x*8 + uwave()*2;
  if (v0 >= n) return;                        // uniform
  int v1 = v0 + 1;
  bool has1 = v1 < n;
  if (!has1) v1 = v0;
  int cn0 = cnt[v0], cn1 = cnt[v1];
  int c0 = min(cn0, CAP), c1 = min(cn1, CAP);
  int ureg0 = n, ureg1 = n;                   // pad -> zero row
  if (lane < c0) ureg0 = (adj + (size_t)v0*CAP)[lane];
  if (lane < c1) ureg1 = (adj + (size_t)v1*CAP)[lane];
  int g = lane >> 3, q = lane & 7;
  float a0[8] = {0,0,0,0,0,0,0,0}, a1[8] = {0,0,0,0,0,0,0,0};
  int itm = (max(c0, c1) + 7) >> 3;
  #pragma unroll 2
  for (int jj = 0; jj < itm; jj++){
    int u0 = __shfl(ureg0, jj*8 + g);
    int u1 = __shfl(ureg1, jj*8 + g);
    uint4 r0 = ((const uint4*)(t + (size_t)u0*64))[q];    // both in flight
    uint4 r1 = ((const uint4*)(t + (size_t)u1*64))[q];
    a0[0] += bfl(r0.x); a0[1] += bfh(r0.x); a0[2] += bfl(r0.y); a0[3] += bfh(r0.y);
    a0[4] += bfl(r0.z); a0[5] += bfh(r0.z); a0[6] += bfl(r0.w); a0[7] += bfh(r0.w);
    a1[0] += bfl(r1.x); a1[1] += bfh(r1.x); a1[2] += bfl(r1.y); a1[3] += bfh(r1.y);
    a1[4] += bfl(r1.z); a1[5] += bfh(r1.z); a1[6] += bfl(r1.w); a1[7] += bfh(r1.w);
  }
  #pragma unroll
  for (int off = 8; off <= 32; off <<= 1){
    #pragma unroll
    for (int k = 0; k < 8; k++){
      a0[k] += __shfl_xor(a0[k], off);
      a1[k] += __shfl_xor(a1[k], off);
    }
  }
  uint4 s0 = ((const uint4*)(t + (size_t)v0*64))[q];      // self rows (L2-hot)
  uint4 s1 = ((const uint4*)(t + (size_t)v1*64))[q];
  a0[0] += bfl(s0.x); a0[1] += bfh(s0.x); a0[2] += bfl(s0.y); a0[3] += bfh(s0.y);
  a0[4] += bfl(s0.z); a0[5] += bfh(s0.z); a0[6] += bfl(s0.w); a0[7] += bfh(s0.w);
  a1[0] += bfl(s1.x); a1[1] += bfh(s1.x); a1[2] += bfl(s1.y); a1[3] += bfh(s1.y);
  a1[4] += bfl(s1.z); a1[5] += bfh(s1.z); a1[6] += bfl(s1.w); a1[7] += bfh(s1.w);
  float dv0 = rsqrtf((float)(cn0 + 1)), dv1 = rsqrtf((float)(cn1 + 1));
  float4 b0 = ((const float4*)b)[2*q], b1v = ((const float4*)b)[2*q+1];
  if (g == 0){
    float r0 = fmaxf(fmaf(a0[0], dv0, b0.x), 0.f),  r1 = fmaxf(fmaf(a0[1], dv0, b0.y), 0.f);
    float r2 = fmaxf(fmaf(a0[2], dv0, b0.z), 0.f),  r3 = fmaxf(fmaf(a0[3], dv0, b0.w), 0.f);
    float r4 = fmaxf(fmaf(a0[4], dv0, b1v.x), 0.f), r5 = fmaxf(fmaf(a0[5], dv0, b1v.y), 0.f);
    float r6 = fmaxf(fmaf(a0[6], dv0, b1v.z), 0.f), r7 = fmaxf(fmaf(a0[7], dv0, b1v.w), 0.f);
    uint4 o;
    o.x = (unsigned)f2bf(r0) | ((unsigned)f2bf(r1) << 16);
    o.y = (unsigned)f2bf(r2) | ((unsigned)f2bf(r3) << 16);
    o.z = (unsigned)f2bf(r4) | ((unsigned)f2bf(r5) << 16);
    o.w = (unsigned)f2bf(r6) | ((unsigned)f2bf(r7) << 16);
    ((uint4*)(h + (size_t)v0*64))[q] = o;                 // 128B store
  } else if (g == 1 && has1){
    float r0 = fmaxf(fmaf(a1[0], dv1, b0.x), 0.f),  r1 = fmaxf(fmaf(a1[1], dv1, b0.y), 0.f);
    float r2 = fmaxf(fmaf(a1[2], dv1, b0.z), 0.f),  r3 = fmaxf(fmaf(a1[3], dv1, b0.w), 0.f);
    float r4 = fmaxf(fmaf(a1[4], dv1, b1v.x), 0.f), r5 = fmaxf(fmaf(a1[5], dv1, b1v.y), 0.f);
    float r6 = fmaxf(fmaf(a1[6], dv1, b1v.z), 0.f), r7 = fmaxf(fmaf(a1[7], dv1, b1v.w), 0.f);
    uint4 o;
    o.x = (unsigned)f2bf(r0) | ((unsigned)f2bf(r1) << 16);
    o.y = (unsigned)f2bf(r2) | ((unsigned)f2bf(r3) << 16);
    o.z = (unsigned)f2bf(r4) | ((unsigned)f2bf(r5) << 16);
    o.w = (unsigned)f2bf(r6) | ((unsigned)f2bf(r7) << 16);
    ((uint4*)(h + (size_t)v1*64))[q] = o;
  }
}

// GAT agg, DUAL-NODE bf16 rows in AND out: 2 softmaxes + interleaved gathers.
__global__ __launch_bounds__(256) void k_gat_agg(const unsigned short* __restrict__ t,
                          const int* __restrict__ adj, const int* __restrict__ cnt,
                          const float* __restrict__ als, const float* __restrict__ ald,
                          const float* __restrict__ b, unsigned short* __restrict__ h, int n){
  int lane = threadIdx.x & 63;
  int v0 = blockIdx.x*8 + uwave()*2;
  if (v0 >= n) return;
  int v1 = v0 + 1;
  bool has1 = v1 < n;
  if (!has1) v1 = v0;
  int c0 = min(cnt[v0], CAP), c1 = min(cnt[v1], CAP);
  int ureg0 = n, ureg1 = n;                   // pad -> zero row
  if (lane < c0) ureg0 = (adj + (size_t)v0*CAP)[lane];
  if (lane < c1) ureg1 = (adj + (size_t)v1*CAP)[lane];
  int us0 = (lane < c0) ? ureg0 : v0;
  int us1 = (lane < c1) ? ureg1 : v1;
  float adv0 = ald[v0], adv1 = ald[v1];       // uniform
  float e0 = als[us0] + adv0;                 // both gathers in flight
  float e1 = als[us1] + adv1;
  e0 = e0 > 0.f ? e0 : 0.2f*e0;
  e1 = e1 > 0.f ? e1 : 0.2f*e1;
  float es0 = als[v0] + adv0; es0 = es0 > 0.f ? es0 : 0.2f*es0;
  float es1 = als[v1] + adv1; es1 = es1 > 0.f ? es1 : 0.2f*es1;
  float em0 = (lane < c0) ? e0 : -1e30f;
  float em1 = (lane < c1) ? e1 : -1e30f;
  #pragma unroll
  for (int off = 32; off; off >>= 1){
    em0 = fmaxf(em0, __shfl_xor(em0, off));
    em1 = fmaxf(em1, __shfl_xor(em1, off));
  }
  em0 = fmaxf(em0, es0); em1 = fmaxf(em1, es1);
  float p0 = (lane < c0) ? __expf(e0 - em0) : 0.f;
  float p1 = (lane < c1) ? __expf(e1 - em1) : 0.f;
  float sm0 = p0, sm1 = p1;
  #pragma unroll
  for (int off = 32; off; off >>= 1){
    sm0 += __shfl_xor(sm0, off);
    sm1 += __shfl_xor(sm1, off);
  }
  float ps0 = __expf(es0 - em0), ps1 = __expf(es1 - em1);
  float inv0 = 1.f / (sm0 + ps0), inv1 = 1.f / (sm1 + ps1);
  int g = lane >> 3, q = lane & 7;
  float a0[8] = {0,0,0,0,0,0,0,0}, a1[8] = {0,0,0,0,0,0,0,0};
  int itm = (max(c0, c1) + 7) >> 3;
  #pragma unroll 2
  for (int jj = 0; jj < itm; jj++){
    int   u0 = __shfl(ureg0, jj*8 + g);
    int   u1 = __shfl(ureg1, jj*8 + g);
    float w0 = __shfl(p0,    jj*8 + g);       // pad slots p=0
    float w1 = __shfl(p1,    jj*8 + g);
    uint4 r0 = ((const uint4*)(t + (size_t)u0*64))[q];
    uint4 r1 = ((const uint4*)(t + (size_t)u1*64))[q];
    a0[0] = fmaf(w0, bfl(r0.x), a0[0]); a0[1] = fmaf(w0, bfh(r0.x), a0[1]);
    a0[2] = fmaf(w0, bfl(r0.y), a0[2]); a0[3] = fmaf(w0, bfh(r0.y), a0[3]);
    a0[4] = fmaf(w0, bfl(r0.z), a0[4]); a0[5] = fmaf(w0, bfh(r0.z), a0[5]);
    a0[6] = fmaf(w0, bfl(r0.w), a0[6]); a0[7] = fmaf(w0, bfh(r0.w), a0[7]);
    a1[0] = fmaf(w1, bfl(r1.x), a1[0]); a1[1] = fmaf(w1, bfh(r1.x), a1[1]);
    a1[2] = fmaf(w1, bfl(r1.y), a1[2]); a1[3] = fmaf(w1, bfh(r1.y), a1[3]);
    a1[4] = fmaf(w1, bfl(r1.z), a1[4]); a1[5] = fmaf(w1, bfh(r1.z), a1[5]);
    a1[6] = fmaf(w1, bfl(r1.w), a1[6]); a1[7] = fmaf(w1, bfh(r1.w), a1[7]);
  }
  #pragma unroll
  for (int off = 8; off <= 32; off <<= 1){
    #pragma unroll
    for (int k = 0; k < 8; k++){
      a0[k] += __shfl_xor(a0[k], off);
      a1[k] += __shfl_xor(a1[k], off);
    }
  }
  uint4 s0 = ((const uint4*)(t + (size_t)v0*64))[q];      // self rows
  uint4 s1 = ((const uint4*)(t + (size_t)v1*64))[q];
  a0[0] = fmaf(ps0, bfl(s0.x), a0[0]); a0[1] = fmaf(ps0, bfh(s0.x), a0[1]);
  a0[2] = fmaf(ps0, bfl(s0.y), a0[2]); a0[3] = fmaf(ps0, bfh(s0.y), a0[3]);
  a0[4] = fmaf(ps0, bfl(s0.z), a0[4]); a0[5] = fmaf(ps0, bfh(s0.z), a0[5]);
  a0[6] = fmaf(ps0, bfl(s0.w), a0[6]); a0[7] = fmaf(ps0, bfh(s0.w), a0[7]);
  a1[0] = fmaf(ps1, bfl(s1.x), a1[0]); a1[1] = fmaf(ps1, bfh(s1.x), a1[1]);
  a1[2] = fmaf(ps1, bfl(s1.y), a1[2]); a1[3] = fmaf(ps1, bfh(s1.y), a1[3]);
  a1[4] = fmaf(ps1, bfl(s1.z), a1[4]); a1[5] = fmaf(ps1, bfh(s1.z), a1[5]);
  a1[6] = fmaf(ps1, bfl(s1.w), a1[6]); a1[7] = fmaf(ps1, bfh(s1.w), a1[7]);
  float4 b0 = ((const float4*)b)[2*q], b1v = ((const float4*)b)[2*q+1];
  if (g == 0){
    float r0 = fmaxf(fmaf(a0[0], inv0, b0.x), 0.f),  r1 = fmaxf(fmaf(a0[1], inv0, b0.y), 0.f);
    float r2 = fmaxf(fmaf(a0[2], inv0, b0.z), 0.f),  r3 = fmaxf(fmaf(a0[3], inv0, b0.w), 0.f);
    float r4 = fmaxf(fmaf(a0[4], inv0, b1v.x), 0.f), r5 = fmaxf(fmaf(a0[5], inv0, b1v.y), 0.f);
    float r6 = fmaxf(fmaf(a0[6], inv0, b1v.z), 0.f), r7 = fmaxf(fmaf(a0[7], inv0, b1v.w), 0.f);
    uint4 o;
    o.x = (unsigned)f2bf(r0) | ((unsigned)f2bf(r1) << 16);
    o.y = (unsigned)f2bf(r2) | ((unsigned)f2bf(r3) << 16);
    o.z = (unsigned)f2bf(r4) | ((unsigned)f2bf(r5) << 16);
    o.w = (unsigned)f2bf(r6) | ((unsigned)f2bf(r7) << 16);
    ((uint4*)(h + (size_t)v0*64))[q] = o;
  } else if (g == 1 && has1){
    float r0 = fmaxf(fmaf(a1[0], inv1, b0.x), 0.f),  r1 = fmaxf(fmaf(a1[1], inv1, b0.y), 0.f);
    float r2 = fmaxf(fmaf(a1[2], inv1, b0.z), 0.f),  r3 = fmaxf(fmaf(a1[3], inv1, b0.w), 0.f);
    float r4 = fmaxf(fmaf(a1[4], inv1, b1v.x), 0.f), r5 = fmaxf(fmaf(a1[5], inv1, b1v.y), 0.f);
    float r6 = fmaxf(fmaf(a1[6], inv1, b1v.z), 0.f), r7 = fmaxf(fmaf(a1[7], inv1, b1v.w), 0.f);
    uint4 o;
    o.x = (unsigned)f2bf(r0) | ((unsigned)f2bf(r1) << 16);
    o.y = (unsigned)f2bf(r2) | ((unsigned)f2bf(r3) << 16);
    o.z = (unsigned)f2bf(r4) | ((unsigned)f2bf(r5) << 16);
    o.w = (unsigned)f2bf(r6) | ((unsigned)f2bf(r7) << 16);
    ((uint4*)(h + (size_t)v1*64))[q] = o;
  }
}

// heads: gemm_alpha-mirror structure (dense Wcat/bcat, resident wreg[64]), bf16 h.
__global__ __launch_bounds__(256, 4) void k_heads(const unsigned short* __restrict__ h,
                        const float* __restrict__ Wcat, const float* __restrict__ bcat,
                        const float* __restrict__ Wb2, const float* __restrict__ bb2,
                        float* __restrict__ out_opt, float* __restrict__ out_bot, int n){
  int lane = threadIdx.x & 63;
  int gw = blockIdx.x*4 + uwave();
  int nw = gridDim.x*4;
  float wreg[64];
  #pragma unroll
  for (int k = 0; k < 64; k++) wreg[k] = Wcat[k*64 + lane];
  float bcr  = bcat[lane];
  float wb2r = (lane >= 32) ? Wb2[lane-32] : 0.f;
  float bb2r = bb2[0];
  for (int v = gw; v < n; v += nw){
    const uint4* xr = (const uint4*)(h + (size_t)v*64);   // uniform row, 8x16B
    float acc = bcr;
    #pragma unroll
    for (int k8 = 0; k8 < 8; k8++){
      uint4 c = xr[k8];
      acc = fmaf(bfl(c.x), wreg[k8*8+0], acc);
      acc = fmaf(bfh(c.x), wreg[k8*8+1], acc);
      acc = fmaf(bfl(c.y), wreg[k8*8+2], acc);
      acc = fmaf(bfh(c.y), wreg[k8*8+3], acc);
      acc = fmaf(bfl(c.z), wreg[k8*8+4], acc);
      acc = fmaf(bfh(c.z), wreg[k8*8+5], acc);
      acc = fmaf(bfl(c.w), wreg[k8*8+6], acc);
      acc = fmaf(bfh(c.w), wreg[k8*8+7], acc);
    }
    if (lane < 10) out_opt[(size_t)v*10 + lane] = acc;
    float contrib = fmaxf(acc, 0.f) * wb2r;   // 0 for lanes<32
    #pragma unroll
    for (int off = 32; off; off >>= 1) contrib += __shfl_xor(contrib, off);
    if (lane == 0) out_bot[v] = 1.f / (1.f + __expf(-(contrib + bb2r)));
  }
}

// mean embedding partials over bf16 h: block-reduce, 64-addr atomics
__global__ __launch_bounds__(256) void k_mean(const unsigned short* __restrict__ h,
                       float* __restrict__ emb_acc, int n){
  __shared__ float red[256];
  int tid = threadIdx.x;
  int w = tid >> 6, lane = tid & 63;
  float s = 0.f;
  for (int r = blockIdx.x*4 + w; r < n; r += 1024)
    s += __uint_as_float(((unsigned)h[(size_t)r*64 + lane]) << 16);
  red[tid] = s;
  __syncthreads();
  if (tid < 64)
    atomicAdd(&emb_acc[tid], red[tid] + red[64+tid] + red[128+tid] + red[192+tid]);
}

__global__ void k_embed(const float* __restrict__ emb_acc, float* __restrict__ out_emb,
                        float invn){
  if (threadIdx.x < 64) out_emb[threadIdx.x] = emb_acc[threadIdx.x] * invn;
}

extern "C" void kernel_launch(void* const* d_in, const int* in_sizes, int n_in,
                              void* d_out, int out_size, void* d_ws, size_t ws_size,
                              hipStream_t stream) {
  const float* x    = (const float*)d_in[0];
  const int*   ei   = (const int*)d_in[1];
  const float* W1   = (const float*)d_in[2];
  const float* b1   = (const float*)d_in[3];
  const float* W2   = (const float*)d_in[4];
  const float* a_s  = (const float*)d_in[5];
  const float* a_d  = (const float*)d_in[6];
  const float* b2   = (const float*)d_in[7];
  const float* W3   = (const float*)d_in[8];
  const float* b3   = (const float*)d_in[9];
  const float* Wopt = (const float*)d_in[10];
  const float* bopt = (const float*)d_in[11];
  const float* Wb1  = (const float*)d_in[12];
  const float* bb1  = (const float*)d_in[13];
  const float* Wb2  = (const float*)d_in[14];
  const float* bb2  = (const float*)d_in[15];

  int n = in_sizes[0] / 32;      // 100000
  int e = in_sizes[1] / 2;       // 1250000
  const int* src = ei;
  const int* dst = ei + e;

  char* ws = (char*)d_ws;
  size_t off = 0;
  auto alloc = [&](size_t bytes) -> void* {
    void* p = ws + off;
    off += (bytes + 255) & ~(size_t)255;
    return p;
  };
  int nb2 = (n + NP2 - 1) >> 7;  // 782 buckets
  int*            cnt     = (int*)           alloc((size_t)n * 4);
  int*            adj     = (int*)           alloc((size_t)n * CAP * 4);
  float*          als     = (float*)         alloc((size_t)n * 4);
  float*          ald     = (float*)         alloc((size_t)n * 4);
  unsigned short* xh      = (unsigned short*)alloc((size_t)(n+1) * 32 * 2); // +zero row
  unsigned short* tb      = (unsigned short*)alloc((size_t)(n+1) * 64 * 2); // +zero row
  unsigned short* hbuf    = (unsigned short*)alloc((size_t)n * 64 * 2);     // bf16 h
  float*          emb_acc = (float*)         alloc((size_t)64 * 4);
  float*          Wcat    = (float*)         alloc((size_t)4096 * 4);
  float*          bcat    = (float*)         alloc((size_t)64 * 4);
  int*            bcnt    = (int*)           alloc((size_t)nb2 * 4);

  // pairs buffer overlays hbuf (pairs consumed by k_fill before k_agg32g writes hbuf)
  int pbcap = e / nb2 + 384;     // mean + ~9 sigma (Binomial per-bucket count)
  long pcap_max = ((long)n * 128) / ((long)nb2 * 8);
  if (pbcap > (int)pcap_max) pbcap = (int)pcap_max;
  uint2* pairs = (uint2*)hbuf;

  float* out_opt = (float*)d_out;
  float* out_bot = out_opt + (size_t)n * 10;
  float* out_emb = out_bot + n;

  int nb8    = (n + 7) / 8;
  int nbN    = (n + 255) / 256;
  int nbP    = (e + 2047) / 2048;  // k_part: 2048 edges/block
  int total4 = n*32/4;
  int nbC    = (total4 + 255) / 256;

  k_setup<<<nbN, 256, 0, stream>>>(Wopt, bopt, Wb1, bb1, Wcat, bcat,
                                   bcnt, tb, xh, emb_acc, n, nb2);
  k_part<<<nbP, 256, 0, stream>>>(src, dst, pairs, bcnt, e, nb2, pbcap);
  k_fill<<<nb2, 256, 0, stream>>>(pairs, bcnt, cnt, adj, pbcap, n);
  k_castscale<<<nbC, 256, 0, stream>>>(x, cnt, xh, total4);

  // layer 1: GCN(32->64) fully fused: dual-node gather + epilogue gemm -> h1 (bf16)
  k_agg32g<<<nb8, 256, 0, stream>>>(xh, adj, cnt, W1, b1, hbuf, n);

  // layer 2: GAT(64->64): gemm -> bf16 t2 + scores, dual-node softmax-gather -> h2
  k_gemm_alpha<<<1024, 256, 0, stream>>>(hbuf, W2, a_s, a_d, tb, als, ald, n);
  k_gat_agg<<<nb8, 256, 0, stream>>>(tb, adj, cnt, als, ald, b2, hbuf, n);

  // layer 3: GCN(64->64): gemm (pre-scaled) -> bf16 t3, dual-node gather -> h3
  k_gemm_b<true><<<1024, 256, 0, stream>>>(hbuf, W3, cnt, tb, n);
  k_gcn_agg<<<nb8, 256, 0, stream>>>(tb, adj, cnt, b3, hbuf, n);

  // heads, mean, final scale
  k_heads<<<1024, 256, 0, stream>>>(hbuf, Wcat, bcat, Wb2, bb2,
                                    out_opt, out_bot, n);
  k_mean<<<256, 256, 0, stream>>>(hbuf, emb_acc, n);
  k_embed<<<1, 64, 0, stream>>>(emb_acc, out_emb, 1.0f / (float)n);
}

// Round 4
// 356.564 us; speedup vs baseline: 1.1588x; 1.0582x over previous
//
#include <hip/hip_runtime.h>
#include <hip/hip_bf16.h>

// WorkflowGNN: GCN(32->64)+ReLU, GAT(64->64,h=1)+ReLU, GCN(64->64)+ReLU,
// heads: opt [N,10], bottleneck [N,1], mean-embed [64]. f32 in/out.
// R20: k_agg32g (57us, BW 14%, VALU 32% -> missing time = per-CU DS pipe:
// ~90 shfl/wave x 195 waves/CU ~ 40% of kernel cycles) -> epilogue's 64
// uniform-lane __shfl broadcasts replaced with v_readlane (VALU pipe, SGPR
// result, bit-identical). DS ops/wave 88->24. Butterfly reduces stay shfl_xor.
// R19 (kept): atomic-free adjacency: k_part bins edges into 782 exact
// dst-buckets (LDS cursors), k_fill builds adj in LDS per bucket, coalesced
// writeout; adj slots beyond cnt are garbage -> never read (lane<c guards).

#define CAP 64
#define NP2 128          // nodes per bucket (LDS tile rows), = 1<<7
#define NB2MAX 800       // LDS cursor array bound (n <= 102400)

__device__ __forceinline__ int uwave(){                 // wave id, known-uniform
  return __builtin_amdgcn_readfirstlane(threadIdx.x >> 6);
}
__device__ __forceinline__ unsigned short f2bf(float f){ // RNE, finite inputs
  unsigned u = __float_as_uint(f);
  return (unsigned short)((u + 0x7fffu + ((u >> 16) & 1u)) >> 16);
}
__device__ __forceinline__ float bfl(unsigned u){ return __uint_as_float(u << 16); }
__device__ __forceinline__ float bfh(unsigned u){ return __uint_as_float(u & 0xffff0000u); }
__device__ __forceinline__ float rdlane(float v, int l){ // uniform-lane broadcast, VALU pipe
  return __uint_as_float(__builtin_amdgcn_readlane(__float_as_uint(v), l));
}

// setup: zero bcnt/pad-rows/emb_acc, pack Wcat/bcat (cnt now written by k_fill)
__global__ void k_setup(const float* __restrict__ Wopt, const float* __restrict__ bopt,
                        const float* __restrict__ Wb1, const float* __restrict__ bb1,
                        float* __restrict__ Wcat, float* __restrict__ bcat,
                        int* __restrict__ bcnt, unsigned short* __restrict__ tb,
                        unsigned short* __restrict__ xh, float* __restrict__ emb_acc,
                        int n, int nb2){
  int i = blockIdx.x*blockDim.x + threadIdx.x;
  if (i < nb2) bcnt[i] = 0;
  if (blockIdx.x == 0){
    int tid = threadIdx.x;
    for (int j = tid; j < 4096; j += 256){    // pack head weights
      int f = j >> 6, c = j & 63;
      float w = 0.f;
      if (c < 10)       w = Wopt[f*10 + c];
      else if (c >= 32) w = Wb1[f*32 + (c-32)];
      Wcat[j] = w;
    }
    if (tid < 64){
      float b = 0.f;
      if (tid < 10)       b = bopt[tid];
      else if (tid >= 32) b = bb1[tid-32];
      bcat[tid] = b;
      tb[(size_t)n*64 + tid] = 0;             // zero pad row (64-feat)
      emb_acc[tid] = 0.f;
    }
    if (tid >= 64 && tid < 96) xh[(size_t)n*32 + (tid-64)] = 0;  // zero pad row (32-feat)
  }
}

// pass A: bin edges into exact dst-range buckets (bk = dst>>7). One coalesced
// read of src/dst (2x int4 each), LDS-aggregated cursors -> ~nb2 global
// atomics per block on 782 hot counters. Writes land on the L2-resident
// cursor frontier (~100KB) -> merge before HBM.
__global__ __launch_bounds__(256) void k_part(const int* __restrict__ src,
                        const int* __restrict__ dst,
                        uint2* __restrict__ pairs, int* __restrict__ bcnt,
                        int e, int nb2, int pbcap){
  __shared__ int lcnt[NB2MAX];
  __shared__ int lbase[NB2MAX];
  int tid = threadIdx.x;
  for (int j = tid; j < nb2; j += 256) lcnt[j] = 0;
  __syncthreads();
  int i0 = blockIdx.x*2048 + tid*8;
  int d[8], s[8], bk[8], lp[8];
  int nv = e - i0;
  if (nv > 8) nv = 8;
  if (nv < 0) nv = 0;
  if (nv == 8){
    int4 d0 = *(const int4*)(dst + i0), d1 = *(const int4*)(dst + i0 + 4);
    int4 s0 = *(const int4*)(src + i0), s1 = *(const int4*)(src + i0 + 4);
    d[0]=d0.x; d[1]=d0.y; d[2]=d0.z; d[3]=d0.w;
    d[4]=d1.x; d[5]=d1.y; d[6]=d1.z; d[7]=d1.w;
    s[0]=s0.x; s[1]=s0.y; s[2]=s0.z; s[3]=s0.w;
    s[4]=s1.x; s[5]=s1.y; s[6]=s1.z; s[7]=s1.w;
  } else {
    #pragma unroll
    for (int j = 0; j < 8; j++){ d[j] = 0; s[j] = 0; }
    for (int j = 0; j < nv; j++){ d[j] = dst[i0+j]; s[j] = src[i0+j]; }
  }
  #pragma unroll
  for (int j = 0; j < 8; j++){
    if (j < nv){
      bk[j] = d[j] >> 7;                      // exact: bucket owns [bk*128, bk*128+128)
      lp[j] = atomicAdd(&lcnt[bk[j]], 1);
    }
  }
  __syncthreads();
  for (int j = tid; j < nb2; j += 256){
    int c = lcnt[j];
    if (c) lbase[j] = atomicAdd(&bcnt[j], c);
  }
  __syncthreads();
  #pragma unroll
  for (int j = 0; j < 8; j++){
    if (j < nv){
      int p = lbase[bk[j]] + lp[j];
      if (p < pbcap)
        pairs[(size_t)bk[j]*pbcap + p] = make_uint2((unsigned)d[j], (unsigned)s[j]);
    }
  }
}

// pass B: one block per bucket. Build 128 adj rows in LDS (LDS atomics only,
// zero global atomics), then write rows + cnt fully coalesced. Slots beyond
// lc[r] are garbage -> never read downstream (lane < c guards).
__global__ __launch_bounds__(256) void k_fill(const uint2* __restrict__ pairs,
                        const int* __restrict__ bcnt, int* __restrict__ cnt,
                        int* __restrict__ adj, int pbcap, int n){
  __shared__ int lc[NP2];
  __shared__ int ladj[NP2*CAP];               // 32KB
  int b = blockIdx.x;
  int lo = b << 7;
  int nn = min(NP2, n - lo);
  int tid = threadIdx.x;
  for (int j = tid; j < NP2; j += 256) lc[j] = 0;
  __syncthreads();
  int m = bcnt[b];
  if (m > pbcap) m = pbcap;
  const uint2* pb = pairs + (size_t)b*pbcap;
  for (int j = tid; j < m; j += 256){
    uint2 p = pb[j];
    int r = (int)p.x - lo;
    int pos = atomicAdd(&lc[r], 1);
    if (pos < CAP) ladj[(r << 6) + pos] = (int)p.y;
  }
  __syncthreads();
  if (tid < nn) cnt[lo + tid] = lc[tid];
  int tot = nn << 4;                          // nn*64 ints / 4 per uint4
  uint4* ga = (uint4*)(adj + (size_t)lo*CAP);
  const uint4* la = (const uint4*)ladj;
  for (int j = tid; j < tot; j += 256) ga[j] = la[j];
}

// cast x -> bf16, pre-scaled by rsqrt(deg): xs[v] = x[v]*rsqrt(cnt[v]+1)
__global__ void k_castscale(const float* __restrict__ x, const int* __restrict__ cnt,
                            unsigned short* __restrict__ xh, int total4){
  int i = blockIdx.x*blockDim.x + threadIdx.x;
  if (i >= total4) return;
  int row = i >> 3;                           // 8 float4 per 32-elem row
  float dv = rsqrtf((float)(cnt[row] + 1));
  float4 v = ((const float4*)x)[i];
  uint2 o;
  o.x = (unsigned)f2bf(v.x*dv) | ((unsigned)f2bf(v.y*dv) << 16);
  o.y = (unsigned)f2bf(v.z*dv) | ((unsigned)f2bf(v.w*dv) << 16);
  ((uint2*)xh)[i] = o;
}

// layer-1 FUSED aggregate+gemm, DUAL-NODE, bf16 out.
// Epilogue broadcasts via v_readlane (VALU) instead of __shfl (DS pipe).
__global__ __launch_bounds__(256) void k_agg32g(const unsigned short* __restrict__ xh,
                          const int* __restrict__ adj, const int* __restrict__ cnt,
                          const float* __restrict__ W1, const float* __restrict__ b1,
                          unsigned short* __restrict__ h, int n){
  int lane = threadIdx.x & 63;
  float wreg[32];
  #pragma unroll
  for (int k = 0; k < 32; k++) wreg[k] = W1[k*64 + lane];  // coalesced, once
  float br = b1[lane];
  int v0 = blockIdx.x*8 + uwave()*2;
  if (v0 >= n) return;                        // uniform
  int v1 = v0 + 1;
  bool has1 = v1 < n;
  if (!has1) v1 = v0;
  int cn0 = cnt[v0], cn1 = cnt[v1];
  int c0 = min(cn0, CAP), c1 = min(cn1, CAP);
  int ureg0 = n, ureg1 = n;                   // pad -> zero row
  if (lane < c0) ureg0 = (adj + (size_t)v0*CAP)[lane];
  if (lane < c1) ureg1 = (adj + (size_t)v1*CAP)[lane];
  int g = lane >> 3, q = lane & 7;
  float4 a0 = {0.f,0.f,0.f,0.f}, a1 = {0.f,0.f,0.f,0.f};
  int itm = (max(c0, c1) + 7) >> 3;
  #pragma unroll 2
  for (int jj = 0; jj < itm; jj++){
    int u0 = __shfl(ureg0, jj*8 + g);         // pad iters -> zero row (L1-hot)
    int u1 = __shfl(ureg1, jj*8 + g);
    uint2 r0 = ((const uint2*)(xh + (size_t)u0*32))[q];   // both loads in flight
    uint2 r1 = ((const uint2*)(xh + (size_t)u1*32))[q];
    a0.x += bfl(r0.x); a0.y += bfh(r0.x); a0.z += bfl(r0.y); a0.w += bfh(r0.y);
    a1.x += bfl(r1.x); a1.y += bfh(r1.x); a1.z += bfl(r1.y); a1.w += bfh(r1.y);
  }
  #pragma unroll
  for (int off = 8; off <= 32; off <<= 1){
    a0.x += __shfl_xor(a0.x, off); a0.y += __shfl_xor(a0.y, off);
    a0.z += __shfl_xor(a0.z, off); a0.w += __shfl_xor(a0.w, off);
    a1.x += __shfl_xor(a1.x, off); a1.y += __shfl_xor(a1.y, off);
    a1.z += __shfl_xor(a1.z, off); a1.w += __shfl_xor(a1.w, off);
  }
  uint2 s0 = ((const uint2*)(xh + (size_t)v0*32))[q];     // self rows (pre-scaled)
  uint2 s1 = ((const uint2*)(xh + (size_t)v1*32))[q];
  a0.x += bfl(s0.x); a0.y += bfh(s0.x); a0.z += bfl(s0.y); a0.w += bfh(s0.y);
  a1.x += bfl(s1.x); a1.y += bfh(s1.x); a1.z += bfl(s1.y); a1.w += bfh(s1.y);
  float dv0 = rsqrtf((float)(cn0 + 1)), dv1 = rsqrtf((float)(cn1 + 1));
  a0.x *= dv0; a0.y *= dv0; a0.z *= dv0; a0.w *= dv0;
  a1.x *= dv1; a1.y *= dv1; a1.z *= dv1; a1.w *= dv1;
  float h0 = br, h1v = br;                    // epilogue gemms via v_readlane (VALU)
  #pragma unroll
  for (int q2 = 0; q2 < 8; q2++){
    float w0x = rdlane(a0.x, q2), w1x = rdlane(a1.x, q2);
    float w0y = rdlane(a0.y, q2), w1y = rdlane(a1.y, q2);
    float w0z = rdlane(a0.z, q2), w1z = rdlane(a1.z, q2);
    float w0w = rdlane(a0.w, q2), w1w = rdlane(a1.w, q2);
    h0 = fmaf(w0x, wreg[q2*4+0], h0); h1v = fmaf(w1x, wreg[q2*4+0], h1v);
    h0 = fmaf(w0y, wreg[q2*4+1], h0); h1v = fmaf(w1y, wreg[q2*4+1], h1v);
    h0 = fmaf(w0z, wreg[q2*4+2], h0); h1v = fmaf(w1z, wreg[q2*4+2], h1v);
    h0 = fmaf(w0w, wreg[q2*4+3], h0); h1v = fmaf(w1w, wreg[q2*4+3], h1v);
  }
  h[(size_t)v0*64 + lane] = f2bf(fmaxf(h0, 0.f));   // 128B coalesced
  if (has1) h[(size_t)v1*64 + lane] = f2bf(fmaxf(h1v, 0.f));
}

// K=64 GEMM (bf16 in) -> bf16 out, optional pre-scale by rsqrt(deg)
template<bool SCALE>
__global__ __launch_bounds__(256, 4) void k_gemm_b(const unsigned short* __restrict__ x,
                       const float* __restrict__ W, const int* __restrict__ cnt,
                       unsigned short* __restrict__ t, int n){
  int lane = threadIdx.x & 63;
  int gw = blockIdx.x*4 + uwave();
  int nw = gridDim.x*4;
  float wreg[64];
  #pragma unroll
  for (int k = 0; k < 64; k++) wreg[k] = W[k*64 + lane];
  for (int v = gw; v < n; v += nw){
    const uint4* xr = (const uint4*)(x + (size_t)v*64);   // uniform row, 8x16B
    float acc = 0.f;
    #pragma unroll
    for (int k8 = 0; k8 < 8; k8++){
      uint4 c = xr[k8];
      acc = fmaf(bfl(c.x), wreg[k8*8+0], acc);
      acc = fmaf(bfh(c.x), wreg[k8*8+1], acc);
      acc = fmaf(bfl(c.y), wreg[k8*8+2], acc);
      acc = fmaf(bfh(c.y), wreg[k8*8+3], acc);
      acc = fmaf(bfl(c.z), wreg[k8*8+4], acc);
      acc = fmaf(bfh(c.z), wreg[k8*8+5], acc);
      acc = fmaf(bfl(c.w), wreg[k8*8+6], acc);
      acc = fmaf(bfh(c.w), wreg[k8*8+7], acc);
    }
    if (SCALE) acc *= rsqrtf((float)(cnt[v] + 1));
    t[(size_t)v*64 + lane] = f2bf(acc);                    // 128B coalesced
  }
}

// K=64 GEMM (bf16 in) -> bf16 out + fused alpha_src/alpha_dst dots (f32 scores)
__global__ __launch_bounds__(256, 4) void k_gemm_alpha(const unsigned short* __restrict__ x,
                       const float* __restrict__ W,
                       const float* __restrict__ asrc, const float* __restrict__ adst,
                       unsigned short* __restrict__ t, float* __restrict__ als,
                       float* __restrict__ ald, int n){
  int lane = threadIdx.x & 63;
  int gw = blockIdx.x*4 + uwave();
  int nw = gridDim.x*4;
  float wreg[64];
  #pragma unroll
  for (int k = 0; k < 64; k++) wreg[k] = W[k*64 + lane];
  float asr = asrc[lane], adr = adst[lane];
  for (int v = gw; v < n; v += nw){
    const uint4* xr = (const uint4*)(x + (size_t)v*64);
    float acc = 0.f;
    #pragma unroll
    for (int k8 = 0; k8 < 8; k8++){
      uint4 c = xr[k8];
      acc = fmaf(bfl(c.x), wreg[k8*8+0], acc);
      acc = fmaf(bfh(c.x), wreg[k8*8+1], acc);
      acc = fmaf(bfl(c.y), wreg[k8*8+2], acc);
      acc = fmaf(bfh(c.y), wreg[k8*8+3], acc);
      acc = fmaf(bfl(c.z), wreg[k8*8+4], acc);
      acc = fmaf(bfh(c.z), wreg[k8*8+5], acc);
      acc = fmaf(bfl(c.w), wreg[k8*8+6], acc);
      acc = fmaf(bfh(c.w), wreg[k8*8+7], acc);
    }
    t[(size_t)v*64 + lane] = f2bf(acc);
    float s1 = acc * asr, s2 = acc * adr;
    #pragma unroll
    for (int off = 32; off; off >>= 1){
      s1 += __shfl_xor(s1, off);
      s2 += __shfl_xor(s2, off);
    }
    if (lane == 0){ als[v] = s1; ald[v] = s2; }
  }
}

// GCN agg (layer 3), DUAL-NODE bf16 rows in AND out.
__global__ __launch_bounds__(256) void k_gcn_agg(const unsigned short* __restrict__ t,
                          const int* __restrict__ adj, const int* __restrict__ cnt,
                          const float* __restrict__ b, unsigned short* __restrict__ h, int n){
  int lane = threadIdx.x & 63;
  int v0 = blockIdx.x*8 + uwave()*2;
  if (v0 >= n) return;                        // uniform
  int v1 = v0 + 1;
  bool has1 = v1 < n;
  if (!has1) v1 = v0;
  int cn0 = cnt[v0], cn1 = cnt[v1];
  int c0 = min(cn0, CAP), c1 = min(cn1, CAP);
  int ureg0 = n, ureg1 = n;                   // pad -> zero row
  if (lane < c0) ureg0 = (adj + (size_t)v0*CAP)[lane];
  if (lane < c1) ureg1 = (adj + (size_t)v1*CAP)[lane];
  int g = lane >> 3, q = lane & 7;
  float a0[8] = {0,0,0,0,0,0,0,0}, a1[8] = {0,0,0,0,0,0,0,0};
  int itm = (max(c0, c1) + 7) >> 3;
  #pragma unroll 2
  for (int jj = 0; jj < itm; jj++){
    int u0 = __shfl(ureg0, jj*8 + g);
    int u1 = __shfl(ureg1, jj*8 + g);
    uint4 r0 = ((const uint4*)(t + (size_t)u0*64))[q];    // both in flight
    uint4 r1 = ((const uint4*)(t + (size_t)u1*64))[q];
    a0[0] += bfl(r0.x); a0[1] += bfh(r0.x); a0[2] += bfl(r0.y); a0[3] += bfh(r0.y);
    a0[4] += bfl(r0.z); a0[5] += bfh(r0.z); a0[6] += bfl(r0.w); a0[7] += bfh(r0.w);
    a1[0] += bfl(r1.x); a1[1] += bfh(r1.x); a1[2] += bfl(r1.y); a1[3] += bfh(r1.y);
    a1[4] += bfl(r1.z); a1[5] += bfh(r1.z); a1[6] += bfl(r1.w); a1[7] += bfh(r1.w);
  }
  #pragma unroll
  for (int off = 8; off <= 32; off <<= 1){
    #pragma unroll
    for (int k = 0; k < 8; k++){
      a0[k] += __shfl_xor(a0[k], off);
      a1[k] += __shfl_xor(a1[k], off);
    }
  }
  uint4 s0 = ((const uint4*)(t + (size_t)v0*64))[q];      // self rows (L2-hot)
  uint4 s1 = ((const uint4*)(t + (size_t)v1*64))[q];
  a0[0] += bfl(s0.x); a0[1] += bfh(s0.x); a0[2] += bfl(s0.y); a0[3] += bfh(s0.y);
  a0[4] += bfl(s0.z); a0[5] += bfh(s0.z); a0[6] += bfl(s0.w); a0[7] += bfh(s0.w);
  a1[0] += bfl(s1.x); a1[1] += bfh(s1.x); a1[2] += bfl(s1.y); a1[3] += bfh(s1.y);
  a1[4] += bfl(s1.z); a1[5] += bfh(s1.z); a1[6] += bfl(s1.w); a1[7] += bfh(s1.w);
  float dv0 = rsqrtf((float)(cn0 + 1)), dv1 = rsqrtf((float)(cn1 + 1));
  float4 b0 = ((const float4*)b)[2*q], b1v = ((const float4*)b)[2*q+1];
  if (g == 0){
    float r0 = fmaxf(fmaf(a0[0], dv0, b0.x), 0.f),  r1 = fmaxf(fmaf(a0[1], dv0, b0.y), 0.f);
    float r2 = fmaxf(fmaf(a0[2], dv0, b0.z), 0.f),  r3 = fmaxf(fmaf(a0[3], dv0, b0.w), 0.f);
    float r4 = fmaxf(fmaf(a0[4], dv0, b1v.x), 0.f), r5 = fmaxf(fmaf(a0[5], dv0, b1v.y), 0.f);
    float r6 = fmaxf(fmaf(a0[6], dv0, b1v.z), 0.f), r7 = fmaxf(fmaf(a0[7], dv0, b1v.w), 0.f);
    uint4 o;
    o.x = (unsigned)f2bf(r0) | ((unsigned)f2bf(r1) << 16);
    o.y = (unsigned)f2bf(r2) | ((unsigned)f2bf(r3) << 16);
    o.z = (unsigned)f2bf(r4) | ((unsigned)f2bf(r5) << 16);
    o.w = (unsigned)f2bf(r6) | ((unsigned)f2bf(r7) << 16);
    ((uint4*)(h + (size_t)v0*64))[q] = o;                 // 128B store
  } else if (g == 1 && has1){
    float r0 = fmaxf(fmaf(a1[0], dv1, b0.x), 0.f),  r1 = fmaxf(fmaf(a1[1], dv1, b0.y), 0.f);
    float r2 = fmaxf(fmaf(a1[2], dv1, b0.z), 0.f),  r3 = fmaxf(fmaf(a1[3], dv1, b0.w), 0.f);
    float r4 = fmaxf(fmaf(a1[4], dv1, b1v.x), 0.f), r5 = fmaxf(fmaf(a1[5], dv1, b1v.y), 0.f);
    float r6 = fmaxf(fmaf(a1[6], dv1, b1v.z), 0.f), r7 = fmaxf(fmaf(a1[7], dv1, b1v.w), 0.f);
    uint4 o;
    o.x = (unsigned)f2bf(r0) | ((unsigned)f2bf(r1) << 16);
    o.y = (unsigned)f2bf(r2) | ((unsigned)f2bf(r3) << 16);
    o.z = (unsigned)f2bf(r4) | ((unsigned)f2bf(r5) << 16);
    o.w = (unsigned)f2bf(r6) | ((unsigned)f2bf(r7) << 16);
    ((uint4*)(h + (size_t)v1*64))[q] = o;
  }
}

// GAT agg, DUAL-NODE bf16 rows in AND out: 2 softmaxes + interleaved gathers.
__global__ __launch_bounds__(256) void k_gat_agg(const unsigned short* __restrict__ t,
                          const int* __restrict__ adj, const int* __restrict__ cnt,
                          const float* __restrict__ als, const float* __restrict__ ald,
                          const float* __restrict__ b, unsigned short* __restrict__ h, int n){
  int lane = threadIdx.x & 63;
  int v0 = blockIdx.x*8 + uwave()*2;
  if (v0 >= n) return;
  int v1 = v0 + 1;
  bool has1 = v1 < n;
  if (!has1) v1 = v0;
  int c0 = min(cnt[v0], CAP), c1 = min(cnt[v1], CAP);
  int ureg0 = n, ureg1 = n;                   // pad -> zero row
  if (lane < c0) ureg0 = (adj + (size_t)v0*CAP)[lane];
  if (lane < c1) ureg1 = (adj + (size_t)v1*CAP)[lane];
  int us0 = (lane < c0) ? ureg0 : v0;
  int us1 = (lane < c1) ? ureg1 : v1;
  float adv0 = ald[v0], adv1 = ald[v1];       // uniform
  float e0 = als[us0] + adv0;                 // both gathers in flight
  float e1 = als[us1] + adv1;
  e0 = e0 > 0.f ? e0 : 0.2f*e0;
  e1 = e1 > 0.f ? e1 : 0.2f*e1;
  float es0 = als[v0] + adv0; es0 = es0 > 0.f ? es0 : 0.2f*es0;
  float es1 = als[v1] + adv1; es1 = es1 > 0.f ? es1 : 0.2f*es1;
  float em0 = (lane < c0) ? e0 : -1e30f;
  float em1 = (lane < c1) ? e1 : -1e30f;
  #pragma unroll
  for (int off = 32; off; off >>= 1){
    em0 = fmaxf(em0, __shfl_xor(em0, off));
    em1 = fmaxf(em1, __shfl_xor(em1, off));
  }
  em0 = fmaxf(em0, es0); em1 = fmaxf(em1, es1);
  float p0 = (lane < c0) ? __expf(e0 - em0) : 0.f;
  float p1 = (lane < c1) ? __expf(e1 - em1) : 0.f;
  float sm0 = p0, sm1 = p1;
  #pragma unroll
  for (int off = 32; off; off >>= 1){
    sm0 += __shfl_xor(sm0, off);
    sm1 += __shfl_xor(sm1, off);
  }
  float ps0 = __expf(es0 - em0), ps1 = __expf(es1 - em1);
  float inv0 = 1.f / (sm0 + ps0), inv1 = 1.f / (sm1 + ps1);
  int g = lane >> 3, q = lane & 7;
  float a0[8] = {0,0,0,0,0,0,0,0}, a1[8] = {0,0,0,0,0,0,0,0};
  int itm = (max(c0, c1) + 7) >> 3;
  #pragma unroll 2
  for (int jj = 0; jj < itm; jj++){
    int   u0 = __shfl(ureg0, jj*8 + g);
    int   u1 = __shfl(ureg1, jj*8 + g);
    float w0 = __shfl(p0,    jj*8 + g);       // pad slots p=0
    float w1 = __shfl(p1,    jj*8 + g);
    uint4 r0 = ((const uint4*)(t + (size_t)u0*64))[q];
    uint4 r1 = ((const uint4*)(t + (size_t)u1*64))[q];
    a0[0] = fmaf(w0, bfl(r0.x), a0[0]); a0[1] = fmaf(w0, bfh(r0.x), a0[1]);
    a0[2] = fmaf(w0, bfl(r0.y), a0[2]); a0[3] = fmaf(w0, bfh(r0.y), a0[3]);
    a0[4] = fmaf(w0, bfl(r0.z), a0[4]); a0[5] = fmaf(w0, bfh(r0.z), a0[5]);
    a0[6] = fmaf(w0, bfl(r0.w), a0[6]); a0[7] = fmaf(w0, bfh(r0.w), a0[7]);
    a1[0] = fmaf(w1, bfl(r1.x), a1[0]); a1[1] = fmaf(w1, bfh(r1.x), a1[1]);
    a1[2] = fmaf(w1, bfl(r1.y), a1[2]); a1[3] = fmaf(w1, bfh(r1.y), a1[3]);
    a1[4] = fmaf(w1, bfl(r1.z), a1[4]); a1[5] = fmaf(w1, bfh(r1.z), a1[5]);
    a1[6] = fmaf(w1, bfl(r1.w), a1[6]); a1[7] = fmaf(w1, bfh(r1.w), a1[7]);
  }
  #pragma unroll
  for (int off = 8; off <= 32; off <<= 1){
    #pragma unroll
    for (int k = 0; k < 8; k++){
      a0[k] += __shfl_xor(a0[k], off);
      a1[k] += __shfl_xor(a1[k], off);
    }
  }
  uint4 s0 = ((const uint4*)(t + (size_t)v0*64))[q];      // self rows
  uint4 s1 = ((const uint4*)(t + (size_t)v1*64))[q];
  a0[0] = fmaf(ps0, bfl(s0.x), a0[0]); a0[1] = fmaf(ps0, bfh(s0.x), a0[1]);
  a0[2] = fmaf(ps0, bfl(s0.y), a0[2]); a0[3] = fmaf(ps0, bfh(s0.y), a0[3]);
  a0[4] = fmaf(ps0, bfl(s0.z), a0[4]); a0[5] = fmaf(ps0, bfh(s0.z), a0[5]);
  a0[6] = fmaf(ps0, bfl(s0.w), a0[6]); a0[7] = fmaf(ps0, bfh(s0.w), a0[7]);
  a1[0] = fmaf(ps1, bfl(s1.x), a1[0]); a1[1] = fmaf(ps1, bfh(s1.x), a1[1]);
  a1[2] = fmaf(ps1, bfl(s1.y), a1[2]); a1[3] = fmaf(ps1, bfh(s1.y), a1[3]);
  a1[4] = fmaf(ps1, bfl(s1.z), a1[4]); a1[5] = fmaf(ps1, bfh(s1.z), a1[5]);
  a1[6] = fmaf(ps1, bfl(s1.w), a1[6]); a1[7] = fmaf(ps1, bfh(s1.w), a1[7]);
  float4 b0 = ((const float4*)b)[2*q], b1v = ((const float4*)b)[2*q+1];
  if (g == 0){
    float r0 = fmaxf(fmaf(a0[0], inv0, b0.x), 0.f),  r1 = fmaxf(fmaf(a0[1], inv0, b0.y), 0.f);
    float r2 = fmaxf(fmaf(a0[2], inv0, b0.z), 0.f),  r3 = fmaxf(fmaf(a0[3], inv0, b0.w), 0.f);
    float r4 = fmaxf(fmaf(a0[4], inv0, b1v.x), 0.f), r5 = fmaxf(fmaf(a0[5], inv0, b1v.y), 0.f);
    float r6 = fmaxf(fmaf(a0[6], inv0, b1v.z), 0.f), r7 = fmaxf(fmaf(a0[7], inv0, b1v.w), 0.f);
    uint4 o;
    o.x = (unsigned)f2bf(r0) | ((unsigned)f2bf(r1) << 16);
    o.y = (unsigned)f2bf(r2) | ((unsigned)f2bf(r3) << 16);
    o.z = (unsigned)f2bf(r4) | ((unsigned)f2bf(r5) << 16);
    o.w = (unsigned)f2bf(r6) | ((unsigned)f2bf(r7) << 16);
    ((uint4*)(h + (size_t)v0*64))[q] = o;
  } else if (g == 1 && has1){
    float r0 = fmaxf(fmaf(a1[0], inv1, b0.x), 0.f),  r1 = fmaxf(fmaf(a1[1], inv1, b0.y), 0.f);
    float r2 = fmaxf(fmaf(a1[2], inv1, b0.z), 0.f),  r3 = fmaxf(fmaf(a1[3], inv1, b0.w), 0.f);
    float r4 = fmaxf(fmaf(a1[4], inv1, b1v.x), 0.f), r5 = fmaxf(fmaf(a1[5], inv1, b1v.y), 0.f);
    float r6 = fmaxf(fmaf(a1[6], inv1, b1v.z), 0.f), r7 = fmaxf(fmaf(a1[7], inv1, b1v.w), 0.f);
    uint4 o;
    o.x = (unsigned)f2bf(r0) | ((unsigned)f2bf(r1) << 16);
    o.y = (unsigned)f2bf(r2) | ((unsigned)f2bf(r3) << 16);
    o.z = (unsigned)f2bf(r4) | ((unsigned)f2bf(r5) << 16);
    o.w = (unsigned)f2bf(r6) | ((unsigned)f2bf(r7) << 16);
    ((uint4*)(h + (size_t)v1*64))[q] = o;
  }
}

// heads: gemm_alpha-mirror structure (dense Wcat/bcat, resident wreg[64]), bf16 h.
__global__ __launch_bounds__(256, 4) void k_heads(const unsigned short* __restrict__ h,
                        const float* __restrict__ Wcat, const float* __restrict__ bcat,
                        const float* __restrict__ Wb2, const float* __restrict__ bb2,
                        float* __restrict__ out_opt, float* __restrict__ out_bot, int n){
  int lane = threadIdx.x & 63;
  int gw = blockIdx.x*4 + uwave();
  int nw = gridDim.x*4;
  float wreg[64];
  #pragma unroll
  for (int k = 0; k < 64; k++) wreg[k] = Wcat[k*64 + lane];
  float bcr  = bcat[lane];
  float wb2r = (lane >= 32) ? Wb2[lane-32] : 0.f;
  float bb2r = bb2[0];
  for (int v = gw; v < n; v += nw){
    const uint4* xr = (const uint4*)(h + (size_t)v*64);   // uniform row, 8x16B
    float acc = bcr;
    #pragma unroll
    for (int k8 = 0; k8 < 8; k8++){
      uint4 c = xr[k8];
      acc = fmaf(bfl(c.x), wreg[k8*8+0], acc);
      acc = fmaf(bfh(c.x), wreg[k8*8+1], acc);
      acc = fmaf(bfl(c.y), wreg[k8*8+2], acc);
      acc = fmaf(bfh(c.y), wreg[k8*8+3], acc);
      acc = fmaf(bfl(c.z), wreg[k8*8+4], acc);
      acc = fmaf(bfh(c.z), wreg[k8*8+5], acc);
      acc = fmaf(bfl(c.w), wreg[k8*8+6], acc);
      acc = fmaf(bfh(c.w), wreg[k8*8+7], acc);
    }
    if (lane < 10) out_opt[(size_t)v*10 + lane] = acc;
    float contrib = fmaxf(acc, 0.f) * wb2r;   // 0 for lanes<32
    #pragma unroll
    for (int off = 32; off; off >>= 1) contrib += __shfl_xor(contrib, off);
    if (lane == 0) out_bot[v] = 1.f / (1.f + __expf(-(contrib + bb2r)));
  }
}

// mean embedding partials over bf16 h: block-reduce, 64-addr atomics
__global__ __launch_bounds__(256) void k_mean(const unsigned short* __restrict__ h,
                       float* __restrict__ emb_acc, int n){
  __shared__ float red[256];
  int tid = threadIdx.x;
  int w = tid >> 6, lane = tid & 63;
  float s = 0.f;
  for (int r = blockIdx.x*4 + w; r < n; r += 1024)
    s += __uint_as_float(((unsigned)h[(size_t)r*64 + lane]) << 16);
  red[tid] = s;
  __syncthreads();
  if (tid < 64)
    atomicAdd(&emb_acc[tid], red[tid] + red[64+tid] + red[128+tid] + red[192+tid]);
}

__global__ void k_embed(const float* __restrict__ emb_acc, float* __restrict__ out_emb,
                        float invn){
  if (threadIdx.x < 64) out_emb[threadIdx.x] = emb_acc[threadIdx.x] * invn;
}

extern "C" void kernel_launch(void* const* d_in, const int* in_sizes, int n_in,
                              void* d_out, int out_size, void* d_ws, size_t ws_size,
                              hipStream_t stream) {
  const float* x    = (const float*)d_in[0];
  const int*   ei   = (const int*)d_in[1];
  const float* W1   = (const float*)d_in[2];
  const float* b1   = (const float*)d_in[3];
  const float* W2   = (const float*)d_in[4];
  const float* a_s  = (const float*)d_in[5];
  const float* a_d  = (const float*)d_in[6];
  const float* b2   = (const float*)d_in[7];
  const float* W3   = (const float*)d_in[8];
  const float* b3   = (const float*)d_in[9];
  const float* Wopt = (const float*)d_in[10];
  const float* bopt = (const float*)d_in[11];
  const float* Wb1  = (const float*)d_in[12];
  const float* bb1  = (const float*)d_in[13];
  const float* Wb2  = (const float*)d_in[14];
  const float* bb2  = (const float*)d_in[15];

  int n = in_sizes[0] / 32;      // 100000
  int e = in_sizes[1] / 2;       // 1250000
  const int* src = ei;
  const int* dst = ei + e;

  char* ws = (char*)d_ws;
  size_t off = 0;
  auto alloc = [&](size_t bytes) -> void* {
    void* p = ws + off;
    off += (bytes + 255) & ~(size_t)255;
    return p;
  };
  int nb2 = (n + NP2 - 1) >> 7;  // 782 buckets
  int*            cnt     = (int*)           alloc((size_t)n * 4);
  int*            adj     = (int*)           alloc((size_t)n * CAP * 4);
  float*          als     = (float*)         alloc((size_t)n * 4);
  float*          ald     = (float*)         alloc((size_t)n * 4);
  unsigned short* xh      = (unsigned short*)alloc((size_t)(n+1) * 32 * 2); // +zero row
  unsigned short* tb      = (unsigned short*)alloc((size_t)(n+1) * 64 * 2); // +zero row
  unsigned short* hbuf    = (unsigned short*)alloc((size_t)n * 64 * 2);     // bf16 h
  float*          emb_acc = (float*)         alloc((size_t)64 * 4);
  float*          Wcat    = (float*)         alloc((size_t)4096 * 4);
  float*          bcat    = (float*)         alloc((size_t)64 * 4);
  int*            bcnt    = (int*)           alloc((size_t)nb2 * 4);

  // pairs buffer overlays hbuf (pairs consumed by k_fill before k_agg32g writes hbuf)
  int pbcap = e / nb2 + 384;     // mean + ~9 sigma (Binomial per-bucket count)
  long pcap_max = ((long)n * 128) / ((long)nb2 * 8);
  if (pbcap > (int)pcap_max) pbcap = (int)pcap_max;
  uint2* pairs = (uint2*)hbuf;

  float* out_opt = (float*)d_out;
  float* out_bot = out_opt + (size_t)n * 10;
  float* out_emb = out_bot + n;

  int nb8    = (n + 7) / 8;
  int nbN    = (n + 255) / 256;
  int nbP    = (e + 2047) / 2048;  // k_part: 2048 edges/block
  int total4 = n*32/4;
  int nbC    = (total4 + 255) / 256;

  k_setup<<<nbN, 256, 0, stream>>>(Wopt, bopt, Wb1, bb1, Wcat, bcat,
                                   bcnt, tb, xh, emb_acc, n, nb2);
  k_part<<<nbP, 256, 0, stream>>>(src, dst, pairs, bcnt, e, nb2, pbcap);
  k_fill<<<nb2, 256, 0, stream>>>(pairs, bcnt, cnt, adj, pbcap, n);
  k_castscale<<<nbC, 256, 0, stream>>>(x, cnt, xh, total4);

  // layer 1: GCN(32->64) fully fused: dual-node gather + epilogue gemm -> h1 (bf16)
  k_agg32g<<<nb8, 256, 0, stream>>>(xh, adj, cnt, W1, b1, hbuf, n);

  // layer 2: GAT(64->64): gemm -> bf16 t2 + scores, dual-node softmax-gather -> h2
  k_gemm_alpha<<<1024, 256, 0, stream>>>(hbuf, W2, a_s, a_d, tb, als, ald, n);
  k_gat_agg<<<nb8, 256, 0, stream>>>(tb, adj, cnt, als, ald, b2, hbuf, n);

  // layer 3: GCN(64->64): gemm (pre-scaled) -> bf16 t3, dual-node gather -> h3
  k_gemm_b<true><<<1024, 256, 0, stream>>>(hbuf, W3, cnt, tb, n);
  k_gcn_agg<<<nb8, 256, 0, stream>>>(tb, adj, cnt, b3, hbuf, n);

  // heads, mean, final scale
  k_heads<<<1024, 256, 0, stream>>>(hbuf, Wcat, bcat, Wb2, bb2,
                                    out_opt, out_bot, n);
  k_mean<<<256, 256, 0, stream>>>(hbuf, emb_acc, n);
  k_embed<<<1, 64, 0, stream>>>(emb_acc, out_emb, 1.0f / (float)n);
}